// Round 10
// baseline (331.082 us; speedup 1.0000x reference)
//
#include <hip/hip_runtime.h>
#include <hip/hip_bf16.h>
#include <hip/hip_fp8.h>

#define BSZ 16384
#define DIM 512
#define NEMB 8192
#define NEG 0.01f
#define NSPLIT 8

typedef __attribute__((ext_vector_type(8))) short short8;
typedef __attribute__((ext_vector_type(4))) float f32x4;
typedef __attribute__((ext_vector_type(4))) int i32x4;
typedef __attribute__((ext_vector_type(8))) int i32x8;

typedef const __attribute__((address_space(1))) void GVT;
typedef __attribute__((address_space(3))) void LVT;

__device__ __forceinline__ void gl_lds16(const void* g, void* l) {
    __builtin_amdgcn_global_load_lds((GVT*)g, (LVT*)l, 16, 0, 0);
}

__device__ __forceinline__ float bf2f(unsigned short u) {
    union { unsigned int i; float f; } c; c.i = ((unsigned int)u) << 16; return c.f;
}
__device__ __forceinline__ unsigned short f2bf(float f) {
    union { __hip_bfloat16 h; unsigned short u; } c; c.h = __float2bfloat16(f); return c.u;
}
__device__ __forceinline__ unsigned char f2fp8(float f) {
    __hip_fp8_e4m3 t(f); return (unsigned char)t.__x;
}
// monotone-orderable uint key for a float
__device__ __forceinline__ unsigned int fkey(float f) {
    unsigned int u = __float_as_uint(f);
    return u ^ ((unsigned int)((int)u >> 31) | 0x80000000u);
}

// packed fragment address for element (r, k) of an [R x 512] fp8 matrix.
__device__ __forceinline__ size_t pack_addr(int r, int k) {
    int kg = k >> 6, ko = k & 63;
    int half = ko >> 5, lq = (ko & 31) >> 3, sub = ko & 7;
    int L = lq * 16 + (r & 15);
    return ((size_t)((r >> 4) * 8 + kg) << 10) + (size_t)(L << 4) + (half << 3) + sub;
}

// entry barrier: my 4 loads for the tile I'm about to read are done,
// next tile's 4 stay in flight (per-wave vmcnt + barrier = all waves' quarters in)
__device__ __forceinline__ void vm4_barrier() {
    asm volatile("s_waitcnt vmcnt(4) lgkmcnt(0)\ns_barrier" ::: "memory");
}
__device__ __forceinline__ void vm0_barrier() {
    asm volatile("s_waitcnt vmcnt(0) lgkmcnt(0)\ns_barrier" ::: "memory");
}

// stage one 32-col B tile (16 KB) into LDS buffer BUF: 4 DMA per wave
#define ISSUE_NT(NT, BUF) do { \
    const unsigned char* src_ = gB0p + (size_t)(NT) * 16384; \
    _Pragma("unroll") for (int i_ = 0; i_ < 4; i_++) \
        gl_lds16(src_ + i_ * 1024, &sB8[BUF][uWd + i_ * 1024]); \
} while (0)

// load the 2 column-fragments (ci=0,1) at K-pair KP from LDS tile CUR
#define LOADH(F0, F1, CUR, KP) do { \
    const unsigned char* lb_ = &sB8[CUR][(2 * (KP)) * 1024] + (lane << 4); \
    i32x4 a0_ = *(const i32x4*)lb_; \
    i32x4 a1_ = *(const i32x4*)(lb_ + 1024); \
    i32x4 b0_ = *(const i32x4*)(lb_ + 8192); \
    i32x4 b1_ = *(const i32x4*)(lb_ + 8192 + 1024); \
    F0 = __builtin_shufflevector(a0_, a1_, 0, 1, 2, 3, 4, 5, 6, 7); \
    F1 = __builtin_shufflevector(b0_, b1_, 0, 1, 2, 3, 4, 5, 6, 7); \
} while (0)

// 4 MFMAs: 2 mi row-groups x 2 ci. FIRST=1 -> zero C-in (no acc pre-zeroing).
#define MFMA4(F0, F1, KP, FIRST) do { \
    __builtin_amdgcn_s_setprio(1); \
    _Pragma("unroll") for (int mi = 0; mi < 2; mi++) { \
        f32x4 c0_ = (FIRST) ? Z4 : acc[mi][0]; \
        f32x4 c1_ = (FIRST) ? Z4 : acc[mi][1]; \
        acc[mi][0] = __builtin_amdgcn_mfma_scale_f32_16x16x128_f8f6f4( \
            fa8[mi][KP], F0, c0_, 0, 0, 0, 0x7F7F7F7Fu, 0, 0x7F7F7F7Fu); \
        acc[mi][1] = __builtin_amdgcn_mfma_scale_f32_16x16x128_f8f6f4( \
            fa8[mi][KP], F1, c1_, 0, 0, 0, 0x7F7F7F7Fu, 0, 0x7F7F7F7Fu); \
    } \
    __builtin_amdgcn_s_setprio(0); \
} while (0)

// K=512 for one 32-col tile: 4 K-pairs, PING-PONG fb pairs so each ds_read
// hides under the previous MFMA cluster instead of serializing.
#define COMPUTE(CUR) do { \
    LOADH(fA0, fA1, CUR, 0); \
    LOADH(fB0, fB1, CUR, 1); \
    MFMA4(fA0, fA1, 0, 1); \
    LOADH(fA0, fA1, CUR, 2); \
    MFMA4(fB0, fB1, 1, 0); \
    LOADH(fB0, fB1, CUR, 3); \
    MFMA4(fA0, fA1, 2, 0); \
    MFMA4(fB0, fB1, 3, 0); \
} while (0)

// fold one 32-col tile into s/pbest: 2-col tree, one fkey pack per row.
// Strict inequalities keep first-occurrence semantics exactly.
#define EPILOGUE(NT) do { \
    int j0 = ((NT) << 5) + l15; \
    if (is_logits) { \
        float bb0 = sAux[j0], bb1 = sAux[j0 + 16]; \
        unsigned int ic0 = (unsigned int)(NEMB - 1 - (nbase + j0)); \
        _Pragma("unroll") for (int mi = 0; mi < 2; mi++) \
            _Pragma("unroll") for (int rg = 0; rg < 4; rg++) { \
                float v0 = acc[mi][0][rg] + bb0; \
                float v1 = acc[mi][1][rg] + bb1; \
                int r = mi * 4 + rg; \
                s[r] += __expf(v0) + __expf(v1); \
                float m = fmaxf(v0, v1); \
                unsigned int ii = v1 > v0 ? ic0 - 16 : ic0; \
                unsigned int pk = (fkey(m) & 0xFFFFE000u) | ii; \
                pbest[r] = pbest[r] > pk ? pbest[r] : pk; \
            } \
    } else { \
        float en0 = sAux[j0], en1 = sAux[j0 + 16]; \
        unsigned int cl0 = (unsigned int)(nbase + j0); \
        _Pragma("unroll") for (int mi = 0; mi < 2; mi++) \
            _Pragma("unroll") for (int rg = 0; rg < 4; rg++) { \
                float v0 = fmaf(-2.f, acc[mi][0][rg], en0); \
                float v1 = fmaf(-2.f, acc[mi][1][rg], en1); \
                float m = fminf(v0, v1); \
                unsigned int ii = v1 < v0 ? cl0 + 16 : cl0; \
                unsigned int pk = (fkey(m) & 0xFFFFE000u) | ii; \
                int r = mi * 4 + rg; \
                pbest[r] = pbest[r] < pk ? pbest[r] : pk; \
            } \
    } \
} while (0)

// ---------------- prep: converts + enorm + zero accumulators ----------------
__global__ void k_prep(const float* __restrict__ eeg, const float* __restrict__ mel,
                       const float* __restrict__ emb, const float* __restrict__ W2,
                       const float* __restrict__ W1,
                       unsigned short* __restrict__ o_eeg, unsigned short* __restrict__ o_w1,
                       unsigned char* __restrict__ o_mel8, unsigned char* __restrict__ o_emb8,
                       unsigned char* __restrict__ o_w28,
                       float* __restrict__ enorm,
                       float* __restrict__ acc2, int* __restrict__ cnt) {
    int bid = blockIdx.x, tid = threadIdx.x;
    if (bid == 0 && tid == 0) { acc2[0] = 0.f; acc2[1] = 0.f; *cnt = 0; }
    if (bid < 1024) {
        const int n_big = BSZ * DIM / 4;
        const int n_mid = NEMB * DIM / 4;
        const int n_w1  = DIM * DIM / 4;
        const int total = n_big * 2 + n_mid * 2 + n_w1;
        for (int i = bid * 256 + tid; i < total; i += 1024 * 256) {
            int j = i;
            if (j < n_big) {                      // eeg -> bf16 linear
                float4 v = ((const float4*)eeg)[j];
                ushort4 o; o.x = f2bf(v.x); o.y = f2bf(v.y); o.z = f2bf(v.z); o.w = f2bf(v.w);
                ((ushort4*)o_eeg)[j] = o;
            } else if ((j -= n_big) < n_w1) {     // W1 -> bf16 linear
                float4 v = ((const float4*)W1)[j];
                ushort4 o; o.x = f2bf(v.x); o.y = f2bf(v.y); o.z = f2bf(v.z); o.w = f2bf(v.w);
                ((ushort4*)o_w1)[j] = o;
            } else if ((j -= n_w1) < n_big) {     // mel -> fp8 packed
                float4 v = ((const float4*)mel)[j];
                uchar4 o; o.x = f2fp8(v.x); o.y = f2fp8(v.y); o.z = f2fp8(v.z); o.w = f2fp8(v.w);
                *(uchar4*)(o_mel8 + pack_addr(j >> 7, (j & 127) * 4)) = o;
            } else if ((j -= n_big) < n_mid) {    // emb -> fp8 packed
                float4 v = ((const float4*)emb)[j];
                uchar4 o; o.x = f2fp8(v.x); o.y = f2fp8(v.y); o.z = f2fp8(v.z); o.w = f2fp8(v.w);
                *(uchar4*)(o_emb8 + pack_addr(j >> 7, (j & 127) * 4)) = o;
            } else {                              // W2 -> fp8 packed
                j -= n_mid;
                float4 v = ((const float4*)W2)[j];
                uchar4 o; o.x = f2fp8(v.x); o.y = f2fp8(v.y); o.z = f2fp8(v.z); o.w = f2fp8(v.w);
                *(uchar4*)(o_w28 + pack_addr(j >> 7, (j & 127) * 4)) = o;
            }
        }
    } else {
        // enorm: 8 rows per block, 2 per wave
        int w = tid >> 6, lane = tid & 63;
        int row0 = (bid - 1024) * 8 + w * 2;
        #pragma unroll
        for (int t = 0; t < 2; t++) {
            int row = row0 + t;
            const float4* p = (const float4*)(emb + (size_t)row * DIM) + lane * 2;
            float4 a = p[0], b = p[1];
            float s = a.x*a.x + a.y*a.y + a.z*a.z + a.w*a.w
                    + b.x*b.x + b.y*b.y + b.z*b.z + b.w*b.w;
            #pragma unroll
            for (int d = 1; d < 64; d <<= 1) s += __shfl_xor(s, d);
            if (lane == 0) enorm[row] = s;
        }
    }
}

// ---------------- h = LeakyReLU(eeg @ W1^T + b1): bf16 + packed fp8 out ----------------
__launch_bounds__(256, 2)
__global__ void k_hgemm(const unsigned short* __restrict__ A,
                        const unsigned short* __restrict__ B,
                        const float* __restrict__ b1,
                        unsigned short* __restrict__ H,
                        unsigned char* __restrict__ H8) {
    __shared__ __align__(16) unsigned short sA[4096], sB[4096];
    int tid = threadIdx.x;
    int w = tid >> 6, lane = tid & 63;
    int wr = w >> 1, wc = w & 1;
    int lquad = lane >> 4, l15 = lane & 15;
    int mt = blockIdx.x >> 2, nt = blockIdx.x & 3;
    int m0 = mt * 128, n0 = nt * 128;

    int e0 = w * 512 + lane * 8;
    int r0 = e0 >> 5, ce = e0 & 31;
    const unsigned short* gA0 = A + (m0 + r0) * DIM + ce;
    const unsigned short* gA1 = gA0 + 64 * DIM;
    const unsigned short* gB0 = B + (n0 + r0) * DIM + ce;
    const unsigned short* gB1 = gB0 + 64 * DIM;
    unsigned short* lA0 = sA + w * 512;  unsigned short* lA1 = sA + (w + 4) * 512;
    unsigned short* lB0 = sB + w * 512;  unsigned short* lB1 = sB + (w + 4) * 512;

    int offA[4], offB[4];
    #pragma unroll
    for (int i = 0; i < 4; i++) {
        offA[i] = (wr * 64 + i * 16 + l15) * 32 + lquad * 8;
        offB[i] = (wc * 64 + i * 16 + l15) * 32 + lquad * 8;
    }

    f32x4 acc[4][4];
    #pragma unroll
    for (int mi = 0; mi < 4; mi++)
        #pragma unroll
        for (int ni = 0; ni < 4; ni++) acc[mi][ni] = 0;

    for (int kk = 0; kk < 16; kk++) {
        gl_lds16(gA0, lA0); gl_lds16(gA1, lA1);
        gl_lds16(gB0, lB0); gl_lds16(gB1, lB1);
        gA0 += 32; gA1 += 32; gB0 += 32; gB1 += 32;
        __syncthreads();
        short8 af[4], bf_[4];
        #pragma unroll
        for (int i = 0; i < 4; i++) {
            af[i]  = *(const short8*)&sA[offA[i]];
            bf_[i] = *(const short8*)&sB[offB[i]];
        }
        #pragma unroll
        for (int mi = 0; mi < 4; mi++)
            #pragma unroll
            for (int ni = 0; ni < 4; ni++)
                acc[mi][ni] = __builtin_amdgcn_mfma_f32_16x16x32_bf16(af[mi], bf_[ni], acc[mi][ni], 0, 0, 0);
        __syncthreads();
    }

    #pragma unroll
    for (int ni = 0; ni < 4; ni++) {
        int col = n0 + wc * 64 + ni * 16 + l15;
        float bv = b1[col];
        #pragma unroll
        for (int mi = 0; mi < 4; mi++) {
            int rowb = m0 + wr * 64 + mi * 16 + lquad * 4;
            #pragma unroll
            for (int rg = 0; rg < 4; rg++) {
                float v = acc[mi][ni][rg] + bv;
                v = v >= 0.f ? v : NEG * v;
                H[(rowb + rg) * DIM + col] = f2bf(v);
                H8[pack_addr(rowb + rg, col)] = f2fp8(v);
            }
        }
    }
}

// ---------------- fat GEMM: 4 waves x 32 rows, B LDS-broadcast, triple-buffered ----------------
// R9 skeleton (proven: no spill @ launch_bounds(256,3)) + two incremental changes:
// (1) TRIPLE-buffered LDS B tiles -> the exit lgkm_barrier is gone (one barrier
//     per nt) and the refill issues BEFORE compute (2-nt DMA cover).
// (2) ping-pong fb register pairs -> ds_read latency hides under MFMA clusters.
// Regs ~140 <= 170; LDS 3x16KB + 4KB = 52KB -> 3 blocks/CU (156 <= 160).
__launch_bounds__(256, 3)
__global__ void k_big(const unsigned char* __restrict__ Mel8,
                      const unsigned char* __restrict__ Emb8,
                      const unsigned char* __restrict__ H8,
                      const unsigned char* __restrict__ W28,
                      const float* __restrict__ enorm,
                      const float* __restrict__ b2,
                      float* __restrict__ p_s,
                      unsigned int* __restrict__ p_pmax,
                      unsigned int* __restrict__ p_pmin) {
    __shared__ __align__(16) unsigned char sB8[3][16384];
    __shared__ float sAux[1024];
    int tid = threadIdx.x;
    int w = tid >> 6, lane = tid & 63;
    int lquad = lane >> 4, l15 = lane & 15;
    int bid = blockIdx.x;
    int split = bid & 7;              // XCD-aligned: one split per XCD
    int is_logits = (bid >> 3) & 1;
    int mt = bid >> 4;                // 128 tiles of 128 rows
    int m0 = mt * 128, nbase = split * (NEMB / NSPLIT);

    const unsigned char* gAb = (is_logits ? H8 : Mel8);
    const unsigned char* gBb = (is_logits ? W28 : Emb8);

    // stage aux table (enorm-512 for dist, b2 for logits)
    #pragma unroll
    for (int j = 0; j < 4; j++) {
        int c = tid + j * 256;
        sAux[c] = is_logits ? b2[nbase + c] : (enorm[nbase + c] - 512.0f);
    }

    // A panel -> registers, once. Wave w owns rows [m0+32w, m0+32w+32).
    i32x8 fa8[2][4];
    #pragma unroll
    for (int mi = 0; mi < 2; mi++)
        #pragma unroll
        for (int kp = 0; kp < 4; kp++) {
            const unsigned char* p = gAb
                + ((size_t)(((m0 >> 4) + 2 * w + mi) * 8 + 2 * kp) << 10) + lane * 16;
            i32x4 lo = *(const i32x4*)p;
            i32x4 hi = *(const i32x4*)(p + 1024);
            fa8[mi][kp] = __builtin_shufflevector(lo, hi, 0, 1, 2, 3, 4, 5, 6, 7);
        }

    int uWd = w * 4096;  // wave's quarter of the 16 KB tile (bytes)
    const unsigned char* gB0p = gBb + (size_t)nbase * 512 + uWd + lane * 16;

    __syncthreads();     // aux visible; A/aux vmem drained (vmcnt clean for DMA)

    const f32x4 Z4 = {0.f, 0.f, 0.f, 0.f};
    f32x4 acc[2][2];
    i32x8 fA0, fA1, fB0, fB1;

    float s[8];
    unsigned int pbest[8];
    unsigned int pinit = is_logits ? 0u : 0xFFFFFFFFu;
    #pragma unroll
    for (int r = 0; r < 8; r++) { s[r] = 0.f; pbest[r] = pinit; }

    ISSUE_NT(0, 0);
    ISSUE_NT(1, 1);
    for (int nt = 0; nt < 32; nt++) {
        int cur = nt % 3;
        if (nt < 31) vm4_barrier(); else vm0_barrier();  // tile nt landed (all waves)
        if (nt + 2 < 32) ISSUE_NT(nt + 2, (nt + 2) % 3); // buf (nt-1)%3 is free: read
                                                         // finished before this barrier
        COMPUTE(cur);
        EPILOGUE(nt);      // overlaps other waves' compute; no exit barrier needed
    }

    // each row lives entirely in one wave: l15-group reduce, then direct store
    if (is_logits) {
        #pragma unroll
        for (int r = 0; r < 8; r++)
            #pragma unroll
            for (int d = 1; d < 16; d <<= 1) {
                s[r] += __shfl_xor(s[r], d);
                unsigned int o = (unsigned int)__shfl_xor((int)pbest[r], d);
                pbest[r] = pbest[r] > o ? pbest[r] : o;
            }
        if (l15 == 0) {
            #pragma unroll
            for (int mi = 0; mi < 2; mi++)
                #pragma unroll
                for (int rg = 0; rg < 4; rg++) {
                    int row = w * 32 + mi * 16 + lquad * 4 + rg;
                    int pidx = split * BSZ + m0 + row;
                    p_s[pidx] = s[mi * 4 + rg];
                    p_pmax[pidx] = pbest[mi * 4 + rg];
                }
        }
    } else {
        #pragma unroll
        for (int r = 0; r < 8; r++)
            #pragma unroll
            for (int d = 1; d < 16; d <<= 1) {
                unsigned int o = (unsigned int)__shfl_xor((int)pbest[r], d);
                pbest[r] = pbest[r] < o ? pbest[r] : o;
            }
        if (l15 == 0) {
            #pragma unroll
            for (int mi = 0; mi < 2; mi++)
                #pragma unroll
                for (int rg = 0; rg < 4; rg++) {
                    int row = w * 32 + mi * 16 + lquad * 4 + rg;
                    p_pmin[split * BSZ + m0 + row] = pbest[mi * 4 + rg];
                }
        }
    }
}

// ---------------- tail: merge + gather + global reduce, writes d_out ----------------
__global__ void k_tail(const float* __restrict__ p_s, const unsigned int* __restrict__ p_pmax,
                       const unsigned int* __restrict__ p_pmin,
                       const unsigned short* __restrict__ H,
                       const float* __restrict__ W2,
                       const float* __restrict__ b2,
                       float* __restrict__ acc2, int* __restrict__ cnt,
                       float* __restrict__ out) {
    __shared__ int s_idx[256];
    __shared__ float s_l1[256], s_match[256];
    __shared__ float s_d[4];
    int bid = blockIdx.x, tid = threadIdx.x;
    int w = tid >> 6, lane = tid & 63;
    int r = bid * 256 + tid;

    // merge for own row
    float S = 0.f; unsigned int PM = 0u, PN = 0xFFFFFFFFu;
    #pragma unroll
    for (int sp = 0; sp < NSPLIT; sp++) {
        S += p_s[sp * BSZ + r];
        unsigned int a = p_pmax[sp * BSZ + r];
        PM = PM > a ? PM : a;
        unsigned int b = p_pmin[sp * BSZ + r];
        PN = PN < b ? PN : b;
    }
    int eidx = (NEMB - 1) - (int)(PM & 0x1FFFu);
    int midx = (int)(PN & 0x1FFFu);
    s_idx[tid] = midx;
    s_l1[tid] = __logf(S) - b2[midx];
    s_match[tid] = (eidx == midx) ? 1.f : 0.f;
    __syncthreads();

    // gather: wave w covers rows [w*64, w*64+64); pure per-lane dot partials
    float d0 = 0.f, d1 = 0.f;
    for (int j = 0; j < 64; j++) {
        int rr = w * 64 + j;
        int ridx = s_idx[rr];
        uint4 hv = *(const uint4*)(H + (size_t)(bid * 256 + rr) * DIM + lane * 8);
        const float4* wp = (const float4*)(W2 + (size_t)ridx * DIM + lane * 8);
        float4 w0 = wp[0], w1 = wp[1];
        float p = bf2f((unsigned short)(hv.x & 0xffff)) * w0.x + bf2f((unsigned short)(hv.x >> 16)) * w0.y
                + bf2f((unsigned short)(hv.y & 0xffff)) * w0.z + bf2f((unsigned short)(hv.y >> 16)) * w0.w
                + bf2f((unsigned short)(hv.z & 0xffff)) * w1.x + bf2f((unsigned short)(hv.z >> 16)) * w1.y
                + bf2f((unsigned short)(hv.w & 0xffff)) * w1.z + bf2f((unsigned short)(hv.w >> 16)) * w1.w;
        if (j & 1) d1 += p; else d0 += p;
    }
    float ds = d0 + d1;
    #pragma unroll
    for (int d = 1; d < 64; d <<= 1) ds += __shfl_xor(ds, d);
    if (lane == 0) s_d[w] = ds;

    __syncthreads();
    for (int st = 128; st > 0; st >>= 1) {
        if (tid < st) { s_l1[tid] += s_l1[tid + st]; s_match[tid] += s_match[tid + st]; }
        __syncthreads();
    }
    if (tid == 0) {
        float loss_blk = s_l1[0] - (s_d[0] + s_d[1] + s_d[2] + s_d[3]);
        atomicAdd(&acc2[0], loss_blk * (1.0f / BSZ));
        atomicAdd(&acc2[1], s_match[0] * (1.0f / BSZ));
        __threadfence();
        if (atomicAdd(cnt, 1) == 63) {
            float L = atomicAdd(&acc2[0], 0.f);
            float M = atomicAdd(&acc2[1], 0.f);
            out[0] = L; out[1] = M;
        }
    }
}

extern "C" void kernel_launch(void* const* d_in, const int* in_sizes, int n_in,
                              void* d_out, int out_size, void* d_ws, size_t ws_size,
                              hipStream_t stream) {
    const float* eeg = (const float*)d_in[0];
    const float* mel = (const float*)d_in[1];
    const float* emb = (const float*)d_in[2];
    const float* W1  = (const float*)d_in[3];
    const float* b1  = (const float*)d_in[4];
    const float* W2  = (const float*)d_in[5];
    const float* b2  = (const float*)d_in[6];
    float* out = (float*)d_out;

    unsigned short* ws_eeg = (unsigned short*)d_ws;               // BSZ*DIM bf16
    unsigned short* ws_w1  = ws_eeg + (size_t)BSZ * DIM;          // DIM*DIM bf16
    unsigned short* ws_h   = ws_w1  + (size_t)DIM * DIM;          // BSZ*DIM bf16
    unsigned char*  ws_h8  = (unsigned char*)(ws_h + (size_t)BSZ * DIM);
    unsigned char*  ws_mel8 = ws_h8  + (size_t)BSZ * DIM;
    unsigned char*  ws_emb8 = ws_mel8 + (size_t)BSZ * DIM;
    unsigned char*  ws_w28  = ws_emb8 + (size_t)NEMB * DIM;
    float* ws_en  = (float*)(ws_w28 + (size_t)NEMB * DIM);
    float* p_s    = ws_en + NEMB;
    unsigned int* p_pmax = (unsigned int*)(p_s + (size_t)NSPLIT * BSZ);
    unsigned int* p_pmin = p_pmax + (size_t)NSPLIT * BSZ;
    float* acc2   = (float*)(p_pmin + (size_t)NSPLIT * BSZ);
    int*   cnt    = (int*)(acc2 + 2);

    k_prep<<<2048, 256, 0, stream>>>(eeg, mel, emb, W2, W1,
                                     ws_eeg, ws_w1, ws_mel8, ws_emb8, ws_w28,
                                     ws_en, acc2, cnt);
    k_hgemm<<<(BSZ / 128) * (DIM / 128), 256, 0, stream>>>(ws_eeg, ws_w1, b1, ws_h, ws_h8);
    k_big<<<(BSZ / 128) * NSPLIT * 2, 256, 0, stream>>>(ws_mel8, ws_emb8, ws_h8, ws_w28,
                                                        ws_en, b2, p_s, p_pmax, p_pmin);
    k_tail<<<BSZ / 256, 256, 0, stream>>>(p_s, p_pmax, p_pmin, ws_h, W2, b2, acc2, cnt, out);
}

// Round 11
// 326.815 us; speedup vs baseline: 1.0131x; 1.0131x over previous
//
#include <hip/hip_runtime.h>
#include <hip/hip_bf16.h>
#include <hip/hip_fp8.h>

#define BSZ 16384
#define DIM 512
#define NEMB 8192
#define NEG 0.01f
#define NSPLIT 8

typedef __attribute__((ext_vector_type(8))) short short8;
typedef __attribute__((ext_vector_type(4))) float f32x4;
typedef __attribute__((ext_vector_type(4))) int i32x4;
typedef __attribute__((ext_vector_type(8))) int i32x8;

typedef const __attribute__((address_space(1))) void GVT;
typedef __attribute__((address_space(3))) void LVT;

__device__ __forceinline__ void gl_lds16(const void* g, void* l) {
    __builtin_amdgcn_global_load_lds((GVT*)g, (LVT*)l, 16, 0, 0);
}

__device__ __forceinline__ float bf2f(unsigned short u) {
    union { unsigned int i; float f; } c; c.i = ((unsigned int)u) << 16; return c.f;
}
__device__ __forceinline__ unsigned short f2bf(float f) {
    union { __hip_bfloat16 h; unsigned short u; } c; c.h = __float2bfloat16(f); return c.u;
}
__device__ __forceinline__ unsigned char f2fp8(float f) {
    __hip_fp8_e4m3 t(f); return (unsigned char)t.__x;
}
// monotone-orderable uint key for a float
__device__ __forceinline__ unsigned int fkey(float f) {
    unsigned int u = __float_as_uint(f);
    return u ^ ((unsigned int)((int)u >> 31) | 0x80000000u);
}

// packed fragment address for element (r, k) of an [R x 512] fp8 matrix.
__device__ __forceinline__ size_t pack_addr(int r, int k) {
    int kg = k >> 6, ko = k & 63;
    int half = ko >> 5, lq = (ko & 31) >> 3, sub = ko & 7;
    int L = lq * 16 + (r & 15);
    return ((size_t)((r >> 4) * 8 + kg) << 10) + (size_t)(L << 4) + (half << 3) + sub;
}

// entry barrier: my 4 loads for the tile I'm about to read are done,
// next tile's 4 stay in flight (per-wave vmcnt + barrier = all waves' quarters in)
__device__ __forceinline__ void vm4_barrier() {
    asm volatile("s_waitcnt vmcnt(4) lgkmcnt(0)\ns_barrier" ::: "memory");
}
__device__ __forceinline__ void vm0_barrier() {
    asm volatile("s_waitcnt vmcnt(0) lgkmcnt(0)\ns_barrier" ::: "memory");
}
// exit barrier: all waves done reading the buffer (ds_reads drained)
__device__ __forceinline__ void lgkm_barrier() {
    asm volatile("s_waitcnt lgkmcnt(0)\ns_barrier" ::: "memory");
}

// stage one 32-col B tile (16 KB) into LDS buffer BUF: 4 DMA per wave
#define ISSUE_NT(NT, BUF) do { \
    const unsigned char* src_ = gB0p + (size_t)(NT) * 16384; \
    _Pragma("unroll") for (int i_ = 0; i_ < 4; i_++) \
        gl_lds16(src_ + i_ * 1024, &sB8[BUF][uWd + i_ * 1024]); \
} while (0)

// load the 2 column-fragments (ci=0,1) at K-pair KP from LDS tile CUR
#define LOADH(F0, F1, CUR, KP) do { \
    const unsigned char* lb_ = &sB8[CUR][(2 * (KP)) * 1024] + (lane << 4); \
    i32x4 a0_ = *(const i32x4*)lb_; \
    i32x4 a1_ = *(const i32x4*)(lb_ + 1024); \
    i32x4 b0_ = *(const i32x4*)(lb_ + 8192); \
    i32x4 b1_ = *(const i32x4*)(lb_ + 8192 + 1024); \
    F0 = __builtin_shufflevector(a0_, a1_, 0, 1, 2, 3, 4, 5, 6, 7); \
    F1 = __builtin_shufflevector(b0_, b1_, 0, 1, 2, 3, 4, 5, 6, 7); \
} while (0)

// 4 MFMAs: 2 mi row-groups x 2 ci. FIRST=1 -> zero C-in (no acc pre-zeroing).
#define MFMA4(F0, F1, KP, FIRST) do { \
    __builtin_amdgcn_s_setprio(1); \
    _Pragma("unroll") for (int mi = 0; mi < 2; mi++) { \
        f32x4 c0_ = (FIRST) ? Z4 : acc[mi][0]; \
        f32x4 c1_ = (FIRST) ? Z4 : acc[mi][1]; \
        acc[mi][0] = __builtin_amdgcn_mfma_scale_f32_16x16x128_f8f6f4( \
            fa8[mi][KP], F0, c0_, 0, 0, 0, 0x7F7F7F7Fu, 0, 0x7F7F7F7Fu); \
        acc[mi][1] = __builtin_amdgcn_mfma_scale_f32_16x16x128_f8f6f4( \
            fa8[mi][KP], F1, c1_, 0, 0, 0, 0x7F7F7F7Fu, 0, 0x7F7F7F7Fu); \
    } \
    __builtin_amdgcn_s_setprio(0); \
} while (0)

// K=512 for one 32-col tile: 4 K-pairs, single fb buffer (reg-capped; TLP hides)
#define COMPUTE(CUR) do { \
    LOADH(fB0, fB1, CUR, 0);  MFMA4(fB0, fB1, 0, 1); \
    LOADH(fB0, fB1, CUR, 1);  MFMA4(fB0, fB1, 1, 0); \
    LOADH(fB0, fB1, CUR, 2);  MFMA4(fB0, fB1, 2, 0); \
    LOADH(fB0, fB1, CUR, 3);  MFMA4(fB0, fB1, 3, 0); \
} while (0)

// fold one 32-col tile into s/pbest: 2-col tree, one fkey pack per row.
// Strict inequalities keep first-occurrence semantics exactly.
#define EPILOGUE(NT) do { \
    int j0 = ((NT) << 5) + l15; \
    if (is_logits) { \
        float bb0 = sAux[j0], bb1 = sAux[j0 + 16]; \
        unsigned int ic0 = (unsigned int)(NEMB - 1 - (nbase + j0)); \
        _Pragma("unroll") for (int mi = 0; mi < 2; mi++) \
            _Pragma("unroll") for (int rg = 0; rg < 4; rg++) { \
                float v0 = acc[mi][0][rg] + bb0; \
                float v1 = acc[mi][1][rg] + bb1; \
                int r = mi * 4 + rg; \
                s[r] += __expf(v0) + __expf(v1); \
                float m = fmaxf(v0, v1); \
                unsigned int ii = v1 > v0 ? ic0 - 16 : ic0; \
                unsigned int pk = (fkey(m) & 0xFFFFE000u) | ii; \
                pbest[r] = pbest[r] > pk ? pbest[r] : pk; \
            } \
    } else { \
        float en0 = sAux[j0], en1 = sAux[j0 + 16]; \
        unsigned int cl0 = (unsigned int)(nbase + j0); \
        _Pragma("unroll") for (int mi = 0; mi < 2; mi++) \
            _Pragma("unroll") for (int rg = 0; rg < 4; rg++) { \
                float v0 = fmaf(-2.f, acc[mi][0][rg], en0); \
                float v1 = fmaf(-2.f, acc[mi][1][rg], en1); \
                float m = fminf(v0, v1); \
                unsigned int ii = v1 < v0 ? cl0 + 16 : cl0; \
                unsigned int pk = (fkey(m) & 0xFFFFE000u) | ii; \
                int r = mi * 4 + rg; \
                pbest[r] = pbest[r] < pk ? pbest[r] : pk; \
            } \
    } \
} while (0)

// ---------------- prep: converts + enorm + zero accumulators ----------------
__global__ void k_prep(const float* __restrict__ eeg, const float* __restrict__ mel,
                       const float* __restrict__ emb, const float* __restrict__ W2,
                       const float* __restrict__ W1,
                       unsigned short* __restrict__ o_eeg, unsigned short* __restrict__ o_w1,
                       unsigned char* __restrict__ o_mel8, unsigned char* __restrict__ o_emb8,
                       unsigned char* __restrict__ o_w28,
                       float* __restrict__ enorm,
                       float* __restrict__ acc2, int* __restrict__ cnt) {
    int bid = blockIdx.x, tid = threadIdx.x;
    if (bid == 0 && tid == 0) { acc2[0] = 0.f; acc2[1] = 0.f; *cnt = 0; }
    if (bid < 1024) {
        const int n_big = BSZ * DIM / 4;
        const int n_mid = NEMB * DIM / 4;
        const int n_w1  = DIM * DIM / 4;
        const int total = n_big * 2 + n_mid * 2 + n_w1;
        for (int i = bid * 256 + tid; i < total; i += 1024 * 256) {
            int j = i;
            if (j < n_big) {                      // eeg -> bf16 linear
                float4 v = ((const float4*)eeg)[j];
                ushort4 o; o.x = f2bf(v.x); o.y = f2bf(v.y); o.z = f2bf(v.z); o.w = f2bf(v.w);
                ((ushort4*)o_eeg)[j] = o;
            } else if ((j -= n_big) < n_w1) {     // W1 -> bf16 linear
                float4 v = ((const float4*)W1)[j];
                ushort4 o; o.x = f2bf(v.x); o.y = f2bf(v.y); o.z = f2bf(v.z); o.w = f2bf(v.w);
                ((ushort4*)o_w1)[j] = o;
            } else if ((j -= n_w1) < n_big) {     // mel -> fp8 packed
                float4 v = ((const float4*)mel)[j];
                uchar4 o; o.x = f2fp8(v.x); o.y = f2fp8(v.y); o.z = f2fp8(v.z); o.w = f2fp8(v.w);
                *(uchar4*)(o_mel8 + pack_addr(j >> 7, (j & 127) * 4)) = o;
            } else if ((j -= n_big) < n_mid) {    // emb -> fp8 packed
                float4 v = ((const float4*)emb)[j];
                uchar4 o; o.x = f2fp8(v.x); o.y = f2fp8(v.y); o.z = f2fp8(v.z); o.w = f2fp8(v.w);
                *(uchar4*)(o_emb8 + pack_addr(j >> 7, (j & 127) * 4)) = o;
            } else {                              // W2 -> fp8 packed
                j -= n_mid;
                float4 v = ((const float4*)W2)[j];
                uchar4 o; o.x = f2fp8(v.x); o.y = f2fp8(v.y); o.z = f2fp8(v.z); o.w = f2fp8(v.w);
                *(uchar4*)(o_w28 + pack_addr(j >> 7, (j & 127) * 4)) = o;
            }
        }
    } else {
        // enorm: 8 rows per block, 2 per wave
        int w = tid >> 6, lane = tid & 63;
        int row0 = (bid - 1024) * 8 + w * 2;
        #pragma unroll
        for (int t = 0; t < 2; t++) {
            int row = row0 + t;
            const float4* p = (const float4*)(emb + (size_t)row * DIM) + lane * 2;
            float4 a = p[0], b = p[1];
            float s = a.x*a.x + a.y*a.y + a.z*a.z + a.w*a.w
                    + b.x*b.x + b.y*b.y + b.z*b.z + b.w*b.w;
            #pragma unroll
            for (int d = 1; d < 64; d <<= 1) s += __shfl_xor(s, d);
            if (lane == 0) enorm[row] = s;
        }
    }
}

// ---------------- h = LeakyReLU(eeg @ W1^T + b1): bf16 + packed fp8 out ----------------
__launch_bounds__(256, 2)
__global__ void k_hgemm(const unsigned short* __restrict__ A,
                        const unsigned short* __restrict__ B,
                        const float* __restrict__ b1,
                        unsigned short* __restrict__ H,
                        unsigned char* __restrict__ H8) {
    __shared__ __align__(16) unsigned short sA[4096], sB[4096];
    int tid = threadIdx.x;
    int w = tid >> 6, lane = tid & 63;
    int wr = w >> 1, wc = w & 1;
    int lquad = lane >> 4, l15 = lane & 15;
    int mt = blockIdx.x >> 2, nt = blockIdx.x & 3;
    int m0 = mt * 128, n0 = nt * 128;

    int e0 = w * 512 + lane * 8;
    int r0 = e0 >> 5, ce = e0 & 31;
    const unsigned short* gA0 = A + (m0 + r0) * DIM + ce;
    const unsigned short* gA1 = gA0 + 64 * DIM;
    const unsigned short* gB0 = B + (n0 + r0) * DIM + ce;
    const unsigned short* gB1 = gB0 + 64 * DIM;
    unsigned short* lA0 = sA + w * 512;  unsigned short* lA1 = sA + (w + 4) * 512;
    unsigned short* lB0 = sB + w * 512;  unsigned short* lB1 = sB + (w + 4) * 512;

    int offA[4], offB[4];
    #pragma unroll
    for (int i = 0; i < 4; i++) {
        offA[i] = (wr * 64 + i * 16 + l15) * 32 + lquad * 8;
        offB[i] = (wc * 64 + i * 16 + l15) * 32 + lquad * 8;
    }

    f32x4 acc[4][4];
    #pragma unroll
    for (int mi = 0; mi < 4; mi++)
        #pragma unroll
        for (int ni = 0; ni < 4; ni++) acc[mi][ni] = 0;

    for (int kk = 0; kk < 16; kk++) {
        gl_lds16(gA0, lA0); gl_lds16(gA1, lA1);
        gl_lds16(gB0, lB0); gl_lds16(gB1, lB1);
        gA0 += 32; gA1 += 32; gB0 += 32; gB1 += 32;
        __syncthreads();
        short8 af[4], bf_[4];
        #pragma unroll
        for (int i = 0; i < 4; i++) {
            af[i]  = *(const short8*)&sA[offA[i]];
            bf_[i] = *(const short8*)&sB[offB[i]];
        }
        #pragma unroll
        for (int mi = 0; mi < 4; mi++)
            #pragma unroll
            for (int ni = 0; ni < 4; ni++)
                acc[mi][ni] = __builtin_amdgcn_mfma_f32_16x16x32_bf16(af[mi], bf_[ni], acc[mi][ni], 0, 0, 0);
        __syncthreads();
    }

    #pragma unroll
    for (int ni = 0; ni < 4; ni++) {
        int col = n0 + wc * 64 + ni * 16 + l15;
        float bv = b1[col];
        #pragma unroll
        for (int mi = 0; mi < 4; mi++) {
            int rowb = m0 + wr * 64 + mi * 16 + lquad * 4;
            #pragma unroll
            for (int rg = 0; rg < 4; rg++) {
                float v = acc[mi][ni][rg] + bv;
                v = v >= 0.f ? v : NEG * v;
                H[(rowb + rg) * DIM + col] = f2bf(v);
                H8[pack_addr(rowb + rg, col)] = f2fp8(v);
            }
        }
    }
}

// ---------------- fat GEMM: 4 waves x 32 rows, B LDS-broadcast 32-col tiles ----------------
// R9 kernel verbatim (proven 163 us, MfmaUtil 37%, zero spill): double-buffered
// 16 KB B tiles, vm4 entry barrier + lgkm exit barrier, refill after exit
// barrier flying under the epilogue. launch_bounds(256,3) -> 170 regs/wave.
__launch_bounds__(256, 3)
__global__ void k_big(const unsigned char* __restrict__ Mel8,
                      const unsigned char* __restrict__ Emb8,
                      const unsigned char* __restrict__ H8,
                      const unsigned char* __restrict__ W28,
                      const float* __restrict__ enorm,
                      const float* __restrict__ b2,
                      float* __restrict__ p_s,
                      unsigned int* __restrict__ p_pmax,
                      unsigned int* __restrict__ p_pmin) {
    __shared__ __align__(16) unsigned char sB8[2][16384];
    __shared__ float sAux[1024];
    int tid = threadIdx.x;
    int w = tid >> 6, lane = tid & 63;
    int lquad = lane >> 4, l15 = lane & 15;
    int bid = blockIdx.x;
    int split = bid & 7;              // XCD-aligned: one split per XCD
    int is_logits = (bid >> 3) & 1;
    int mt = bid >> 4;                // 128 tiles of 128 rows
    int m0 = mt * 128, nbase = split * (NEMB / NSPLIT);

    const unsigned char* gAb = (is_logits ? H8 : Mel8);
    const unsigned char* gBb = (is_logits ? W28 : Emb8);

    // stage aux table (enorm-512 for dist, b2 for logits)
    #pragma unroll
    for (int j = 0; j < 4; j++) {
        int c = tid + j * 256;
        sAux[c] = is_logits ? b2[nbase + c] : (enorm[nbase + c] - 512.0f);
    }

    // A panel -> registers, once. Wave w owns rows [m0+32w, m0+32w+32).
    i32x8 fa8[2][4];
    #pragma unroll
    for (int mi = 0; mi < 2; mi++)
        #pragma unroll
        for (int kp = 0; kp < 4; kp++) {
            const unsigned char* p = gAb
                + ((size_t)(((m0 >> 4) + 2 * w + mi) * 8 + 2 * kp) << 10) + lane * 16;
            i32x4 lo = *(const i32x4*)p;
            i32x4 hi = *(const i32x4*)(p + 1024);
            fa8[mi][kp] = __builtin_shufflevector(lo, hi, 0, 1, 2, 3, 4, 5, 6, 7);
        }

    int uWd = w * 4096;  // wave's quarter of the 16 KB tile (bytes)
    const unsigned char* gB0p = gBb + (size_t)nbase * 512 + uWd + lane * 16;

    __syncthreads();     // aux visible; A/aux vmem drained (vmcnt clean for DMA)

    const f32x4 Z4 = {0.f, 0.f, 0.f, 0.f};
    f32x4 acc[2][2];
    i32x8 fB0, fB1;

    float s[8];
    unsigned int pbest[8];
    unsigned int pinit = is_logits ? 0u : 0xFFFFFFFFu;
    #pragma unroll
    for (int r = 0; r < 8; r++) { s[r] = 0.f; pbest[r] = pinit; }

    ISSUE_NT(0, 0);
    ISSUE_NT(1, 1);
    for (int nt = 0; nt < 32; nt++) {
        int cur = nt & 1;
        if (nt < 31) vm4_barrier(); else vm0_barrier();  // tile nt landed (all waves)
        COMPUTE(cur);
        lgkm_barrier();                 // all waves done reading buf[cur]
        if (nt + 2 < 32) ISSUE_NT(nt + 2, cur);  // refill freed buffer; flies under EPI
        EPILOGUE(nt);
    }

    // each row lives entirely in one wave: l15-group reduce, then direct store
    if (is_logits) {
        #pragma unroll
        for (int r = 0; r < 8; r++)
            #pragma unroll
            for (int d = 1; d < 16; d <<= 1) {
                s[r] += __shfl_xor(s[r], d);
                unsigned int o = (unsigned int)__shfl_xor((int)pbest[r], d);
                pbest[r] = pbest[r] > o ? pbest[r] : o;
            }
        if (l15 == 0) {
            #pragma unroll
            for (int mi = 0; mi < 2; mi++)
                #pragma unroll
                for (int rg = 0; rg < 4; rg++) {
                    int row = w * 32 + mi * 16 + lquad * 4 + rg;
                    int pidx = split * BSZ + m0 + row;
                    p_s[pidx] = s[mi * 4 + rg];
                    p_pmax[pidx] = pbest[mi * 4 + rg];
                }
        }
    } else {
        #pragma unroll
        for (int r = 0; r < 8; r++)
            #pragma unroll
            for (int d = 1; d < 16; d <<= 1) {
                unsigned int o = (unsigned int)__shfl_xor((int)pbest[r], d);
                pbest[r] = pbest[r] < o ? pbest[r] : o;
            }
        if (l15 == 0) {
            #pragma unroll
            for (int mi = 0; mi < 2; mi++)
                #pragma unroll
                for (int rg = 0; rg < 4; rg++) {
                    int row = w * 32 + mi * 16 + lquad * 4 + rg;
                    p_pmin[split * BSZ + m0 + row] = pbest[mi * 4 + rg];
                }
        }
    }
}

// ---------------- tail: merge + gather + global reduce, writes d_out ----------------
// 256 blocks x 64 rows (was 64 x 256): 4x the resident waves, gather loop 16
// iterations instead of 64 -> latency-chain cut 4x.
__global__ void k_tail(const float* __restrict__ p_s, const unsigned int* __restrict__ p_pmax,
                       const unsigned int* __restrict__ p_pmin,
                       const unsigned short* __restrict__ H,
                       const float* __restrict__ W2,
                       const float* __restrict__ b2,
                       float* __restrict__ acc2, int* __restrict__ cnt,
                       float* __restrict__ out) {
    __shared__ int s_idx[64];
    __shared__ float s_l1[64], s_match[64];
    __shared__ float s_d[4];
    int bid = blockIdx.x, tid = threadIdx.x;
    int w = tid >> 6, lane = tid & 63;
    int rbase = bid * 64;

    // merge: threads 0..63 each own one row
    if (tid < 64) {
        int r = rbase + tid;
        float S = 0.f; unsigned int PM = 0u, PN = 0xFFFFFFFFu;
        #pragma unroll
        for (int sp = 0; sp < NSPLIT; sp++) {
            S += p_s[sp * BSZ + r];
            unsigned int a = p_pmax[sp * BSZ + r];
            PM = PM > a ? PM : a;
            unsigned int b = p_pmin[sp * BSZ + r];
            PN = PN < b ? PN : b;
        }
        int eidx = (NEMB - 1) - (int)(PM & 0x1FFFu);
        int midx = (int)(PN & 0x1FFFu);
        s_idx[tid] = midx;
        s_l1[tid] = __logf(S) - b2[midx];
        s_match[tid] = (eidx == midx) ? 1.f : 0.f;
    }
    __syncthreads();

    // gather: wave w covers rows [w*16, w*16+16); independent iterations -> MLP
    float d0 = 0.f, d1 = 0.f;
    for (int j = 0; j < 16; j++) {
        int rr = w * 16 + j;
        int ridx = s_idx[rr];
        uint4 hv = *(const uint4*)(H + (size_t)(rbase + rr) * DIM + lane * 8);
        const float4* wp = (const float4*)(W2 + (size_t)ridx * DIM + lane * 8);
        float4 w0 = wp[0], w1 = wp[1];
        float p = bf2f((unsigned short)(hv.x & 0xffff)) * w0.x + bf2f((unsigned short)(hv.x >> 16)) * w0.y
                + bf2f((unsigned short)(hv.y & 0xffff)) * w0.z + bf2f((unsigned short)(hv.y >> 16)) * w0.w
                + bf2f((unsigned short)(hv.z & 0xffff)) * w1.x + bf2f((unsigned short)(hv.z >> 16)) * w1.y
                + bf2f((unsigned short)(hv.w & 0xffff)) * w1.z + bf2f((unsigned short)(hv.w >> 16)) * w1.w;
        if (j & 1) d1 += p; else d0 += p;
    }
    float ds = d0 + d1;
    #pragma unroll
    for (int d = 1; d < 64; d <<= 1) ds += __shfl_xor(ds, d);
    if (lane == 0) s_d[w] = ds;

    __syncthreads();
    for (int st = 32; st > 0; st >>= 1) {
        if (tid < st) { s_l1[tid] += s_l1[tid + st]; s_match[tid] += s_match[tid + st]; }
        __syncthreads();
    }
    if (tid == 0) {
        float loss_blk = s_l1[0] - (s_d[0] + s_d[1] + s_d[2] + s_d[3]);
        atomicAdd(&acc2[0], loss_blk * (1.0f / BSZ));
        atomicAdd(&acc2[1], s_match[0] * (1.0f / BSZ));
        __threadfence();
        if (atomicAdd(cnt, 1) == 255) {
            float L = atomicAdd(&acc2[0], 0.f);
            float M = atomicAdd(&acc2[1], 0.f);
            out[0] = L; out[1] = M;
        }
    }
}

extern "C" void kernel_launch(void* const* d_in, const int* in_sizes, int n_in,
                              void* d_out, int out_size, void* d_ws, size_t ws_size,
                              hipStream_t stream) {
    const float* eeg = (const float*)d_in[0];
    const float* mel = (const float*)d_in[1];
    const float* emb = (const float*)d_in[2];
    const float* W1  = (const float*)d_in[3];
    const float* b1  = (const float*)d_in[4];
    const float* W2  = (const float*)d_in[5];
    const float* b2  = (const float*)d_in[6];
    float* out = (float*)d_out;

    unsigned short* ws_eeg = (unsigned short*)d_ws;               // BSZ*DIM bf16
    unsigned short* ws_w1  = ws_eeg + (size_t)BSZ * DIM;          // DIM*DIM bf16
    unsigned short* ws_h   = ws_w1  + (size_t)DIM * DIM;          // BSZ*DIM bf16
    unsigned char*  ws_h8  = (unsigned char*)(ws_h + (size_t)BSZ * DIM);
    unsigned char*  ws_mel8 = ws_h8  + (size_t)BSZ * DIM;
    unsigned char*  ws_emb8 = ws_mel8 + (size_t)BSZ * DIM;
    unsigned char*  ws_w28  = ws_emb8 + (size_t)NEMB * DIM;
    float* ws_en  = (float*)(ws_w28 + (size_t)NEMB * DIM);
    float* p_s    = ws_en + NEMB;
    unsigned int* p_pmax = (unsigned int*)(p_s + (size_t)NSPLIT * BSZ);
    unsigned int* p_pmin = p_pmax + (size_t)NSPLIT * BSZ;
    float* acc2   = (float*)(p_pmin + (size_t)NSPLIT * BSZ);
    int*   cnt    = (int*)(acc2 + 2);

    k_prep<<<2048, 256, 0, stream>>>(eeg, mel, emb, W2, W1,
                                     ws_eeg, ws_w1, ws_mel8, ws_emb8, ws_w28,
                                     ws_en, acc2, cnt);
    k_hgemm<<<(BSZ / 128) * (DIM / 128), 256, 0, stream>>>(ws_eeg, ws_w1, b1, ws_h, ws_h8);
    k_big<<<(BSZ / 128) * NSPLIT * 2, 256, 0, stream>>>(ws_mel8, ws_emb8, ws_h8, ws_w28,
                                                        ws_en, b2, p_s, p_pmax, p_pmin);
    k_tail<<<BSZ / 64, 256, 0, stream>>>(p_s, p_pmax, p_pmin, ws_h, W2, b2, acc2, cnt, out);
}

// Round 12
// 325.766 us; speedup vs baseline: 1.0163x; 1.0032x over previous
//
#include <hip/hip_runtime.h>
#include <hip/hip_bf16.h>
#include <hip/hip_fp8.h>

#define BSZ 16384
#define DIM 512
#define NEMB 8192
#define NEG 0.01f
#define NSPLIT 8

typedef __attribute__((ext_vector_type(8))) short short8;
typedef __attribute__((ext_vector_type(4))) float f32x4;
typedef __attribute__((ext_vector_type(4))) int i32x4;
typedef __attribute__((ext_vector_type(8))) int i32x8;

typedef const __attribute__((address_space(1))) void GVT;
typedef __attribute__((address_space(3))) void LVT;

__device__ __forceinline__ void gl_lds16(const void* g, void* l) {
    __builtin_amdgcn_global_load_lds((GVT*)g, (LVT*)l, 16, 0, 0);
}

__device__ __forceinline__ float bf2f(unsigned short u) {
    union { unsigned int i; float f; } c; c.i = ((unsigned int)u) << 16; return c.f;
}
__device__ __forceinline__ unsigned short f2bf(float f) {
    union { __hip_bfloat16 h; unsigned short u; } c; c.h = __float2bfloat16(f); return c.u;
}
__device__ __forceinline__ unsigned char f2fp8(float f) {
    __hip_fp8_e4m3 t(f); return (unsigned char)t.__x;
}
// monotone-orderable uint key for a float
__device__ __forceinline__ unsigned int fkey(float f) {
    unsigned int u = __float_as_uint(f);
    return u ^ ((unsigned int)((int)u >> 31) | 0x80000000u);
}

// packed fragment address for element (r, k) of an [R x 512] fp8 matrix.
__device__ __forceinline__ size_t pack_addr(int r, int k) {
    int kg = k >> 6, ko = k & 63;
    int half = ko >> 5, lq = (ko & 31) >> 3, sub = ko & 7;
    int L = lq * 16 + (r & 15);
    return ((size_t)((r >> 4) * 8 + kg) << 10) + (size_t)(L << 4) + (half << 3) + sub;
}

// entry barrier: my 4 loads for the tile I'm about to read are done,
// next tile's 4 stay in flight (per-wave vmcnt + barrier = all waves' quarters in)
__device__ __forceinline__ void vm4_barrier() {
    asm volatile("s_waitcnt vmcnt(4) lgkmcnt(0)\ns_barrier" ::: "memory");
}
__device__ __forceinline__ void vm0_barrier() {
    asm volatile("s_waitcnt vmcnt(0) lgkmcnt(0)\ns_barrier" ::: "memory");
}
// exit barrier: all waves done reading the buffer (ds_reads drained)
__device__ __forceinline__ void lgkm_barrier() {
    asm volatile("s_waitcnt lgkmcnt(0)\ns_barrier" ::: "memory");
}

// stage one 32-col B tile (16 KB) into LDS buffer BUF: 4 DMA per wave
#define ISSUE_NT(NT, BUF) do { \
    const unsigned char* src_ = gB0p + (size_t)(NT) * 16384; \
    _Pragma("unroll") for (int i_ = 0; i_ < 4; i_++) \
        gl_lds16(src_ + i_ * 1024, &sB8[BUF][uWd + i_ * 1024]); \
} while (0)

// load the 2 column-fragments (ci=0,1) at K-pair KP from LDS tile CUR
#define LOADH(F0, F1, CUR, KP) do { \
    const unsigned char* lb_ = &sB8[CUR][(2 * (KP)) * 1024] + (lane << 4); \
    i32x4 a0_ = *(const i32x4*)lb_; \
    i32x4 a1_ = *(const i32x4*)(lb_ + 1024); \
    i32x4 b0_ = *(const i32x4*)(lb_ + 8192); \
    i32x4 b1_ = *(const i32x4*)(lb_ + 8192 + 1024); \
    F0 = __builtin_shufflevector(a0_, a1_, 0, 1, 2, 3, 4, 5, 6, 7); \
    F1 = __builtin_shufflevector(b0_, b1_, 0, 1, 2, 3, 4, 5, 6, 7); \
} while (0)

// 4 MFMAs: 2 mi row-groups x 2 ci. FIRST=1 -> zero C-in (no acc pre-zeroing).
#define MFMA4(F0, F1, KP, FIRST) do { \
    __builtin_amdgcn_s_setprio(1); \
    _Pragma("unroll") for (int mi = 0; mi < 2; mi++) { \
        f32x4 c0_ = (FIRST) ? Z4 : acc[mi][0]; \
        f32x4 c1_ = (FIRST) ? Z4 : acc[mi][1]; \
        acc[mi][0] = __builtin_amdgcn_mfma_scale_f32_16x16x128_f8f6f4( \
            fa8[mi][KP], F0, c0_, 0, 0, 0, 0x7F7F7F7Fu, 0, 0x7F7F7F7Fu); \
        acc[mi][1] = __builtin_amdgcn_mfma_scale_f32_16x16x128_f8f6f4( \
            fa8[mi][KP], F1, c1_, 0, 0, 0, 0x7F7F7F7Fu, 0, 0x7F7F7F7Fu); \
    } \
    __builtin_amdgcn_s_setprio(0); \
} while (0)

// K=512 for one 32-col tile: PING-PONG fA/fB register pairs so LOADH(kp+1)
// issues while MFMA4(kp) runs (breaks the single-buffer WAR serialization).
// Barrier cadence around this is R9's EXACT proven structure.
#define COMPUTE(CUR) do { \
    LOADH(fA0, fA1, CUR, 0); \
    LOADH(fB0, fB1, CUR, 1); \
    MFMA4(fA0, fA1, 0, 1); \
    LOADH(fA0, fA1, CUR, 2); \
    MFMA4(fB0, fB1, 1, 0); \
    LOADH(fB0, fB1, CUR, 3); \
    MFMA4(fA0, fA1, 2, 0); \
    MFMA4(fB0, fB1, 3, 0); \
} while (0)

// fold one 32-col tile into s/pbest: 2-col tree, one fkey pack per row.
// Strict inequalities keep first-occurrence semantics exactly.
#define EPILOGUE(NT) do { \
    int j0 = ((NT) << 5) + l15; \
    if (is_logits) { \
        float bb0 = sAux[j0], bb1 = sAux[j0 + 16]; \
        unsigned int ic0 = (unsigned int)(NEMB - 1 - (nbase + j0)); \
        _Pragma("unroll") for (int mi = 0; mi < 2; mi++) \
            _Pragma("unroll") for (int rg = 0; rg < 4; rg++) { \
                float v0 = acc[mi][0][rg] + bb0; \
                float v1 = acc[mi][1][rg] + bb1; \
                int r = mi * 4 + rg; \
                s[r] += __expf(v0) + __expf(v1); \
                float m = fmaxf(v0, v1); \
                unsigned int ii = v1 > v0 ? ic0 - 16 : ic0; \
                unsigned int pk = (fkey(m) & 0xFFFFE000u) | ii; \
                pbest[r] = pbest[r] > pk ? pbest[r] : pk; \
            } \
    } else { \
        float en0 = sAux[j0], en1 = sAux[j0 + 16]; \
        unsigned int cl0 = (unsigned int)(nbase + j0); \
        _Pragma("unroll") for (int mi = 0; mi < 2; mi++) \
            _Pragma("unroll") for (int rg = 0; rg < 4; rg++) { \
                float v0 = fmaf(-2.f, acc[mi][0][rg], en0); \
                float v1 = fmaf(-2.f, acc[mi][1][rg], en1); \
                float m = fminf(v0, v1); \
                unsigned int ii = v1 < v0 ? cl0 + 16 : cl0; \
                unsigned int pk = (fkey(m) & 0xFFFFE000u) | ii; \
                int r = mi * 4 + rg; \
                pbest[r] = pbest[r] < pk ? pbest[r] : pk; \
            } \
    } \
} while (0)

// ---------------- prep: converts + FUSED enorm + zero accumulators ----------------
// All range boundaries are 256-aligned, so each 256-thread chunk lies entirely
// in one branch; the emb chunk covers exactly 2 rows (threads 0-127 / 128-255),
// letting enorm fold into the convert pass (emb read ONCE, enorm blocks gone).
__global__ void k_prep(const float* __restrict__ eeg, const float* __restrict__ mel,
                       const float* __restrict__ emb, const float* __restrict__ W2,
                       const float* __restrict__ W1,
                       unsigned short* __restrict__ o_eeg, unsigned short* __restrict__ o_w1,
                       unsigned char* __restrict__ o_mel8, unsigned char* __restrict__ o_emb8,
                       unsigned char* __restrict__ o_w28,
                       float* __restrict__ enorm,
                       float* __restrict__ acc2, int* __restrict__ cnt) {
    __shared__ float sps[4];
    int bid = blockIdx.x, tid = threadIdx.x;
    int w = tid >> 6, lane = tid & 63;
    if (bid == 0 && tid == 0) { acc2[0] = 0.f; acc2[1] = 0.f; *cnt = 0; }
    const int n_big = BSZ * DIM / 4;
    const int n_mid = NEMB * DIM / 4;
    const int n_w1  = DIM * DIM / 4;
    const int total = n_big * 2 + n_mid * 2 + n_w1;
    for (int i = bid * 256 + tid; i < total; i += 1024 * 256) {
        int j = i;
        if (j < n_big) {                      // eeg -> bf16 linear
            float4 v = ((const float4*)eeg)[j];
            ushort4 o; o.x = f2bf(v.x); o.y = f2bf(v.y); o.z = f2bf(v.z); o.w = f2bf(v.w);
            ((ushort4*)o_eeg)[j] = o;
        } else if ((j -= n_big) < n_w1) {     // W1 -> bf16 linear
            float4 v = ((const float4*)W1)[j];
            ushort4 o; o.x = f2bf(v.x); o.y = f2bf(v.y); o.z = f2bf(v.z); o.w = f2bf(v.w);
            ((ushort4*)o_w1)[j] = o;
        } else if ((j -= n_w1) < n_big) {     // mel -> fp8 packed
            float4 v = ((const float4*)mel)[j];
            uchar4 o; o.x = f2fp8(v.x); o.y = f2fp8(v.y); o.z = f2fp8(v.z); o.w = f2fp8(v.w);
            *(uchar4*)(o_mel8 + pack_addr(j >> 7, (j & 127) * 4)) = o;
        } else if ((j -= n_big) < n_mid) {    // emb -> fp8 packed + enorm fold
            float4 v = ((const float4*)emb)[j];
            uchar4 o; o.x = f2fp8(v.x); o.y = f2fp8(v.y); o.z = f2fp8(v.z); o.w = f2fp8(v.w);
            *(uchar4*)(o_emb8 + pack_addr(j >> 7, (j & 127) * 4)) = o;
            float ss = v.x*v.x + v.y*v.y + v.z*v.z + v.w*v.w;
            #pragma unroll
            for (int d = 1; d < 64; d <<= 1) ss += __shfl_xor(ss, d);
            if (lane == 0) sps[w] = ss;      // block chunk uniform: safe sync
            __syncthreads();
            if (tid == 0)   enorm[j >> 7]       = sps[0] + sps[1];
            if (tid == 128) enorm[(j >> 7)]     = sps[2] + sps[3];
            __syncthreads();
        } else {                              // W2 -> fp8 packed
            j -= n_mid;
            float4 v = ((const float4*)W2)[j];
            uchar4 o; o.x = f2fp8(v.x); o.y = f2fp8(v.y); o.z = f2fp8(v.z); o.w = f2fp8(v.w);
            *(uchar4*)(o_w28 + pack_addr(j >> 7, (j & 127) * 4)) = o;
        }
    }
}

// ---------------- h = LeakyReLU(eeg @ W1^T + b1): bf16 + packed fp8 out ----------------
__launch_bounds__(256, 2)
__global__ void k_hgemm(const unsigned short* __restrict__ A,
                        const unsigned short* __restrict__ B,
                        const float* __restrict__ b1,
                        unsigned short* __restrict__ H,
                        unsigned char* __restrict__ H8) {
    __shared__ __align__(16) unsigned short sA[4096], sB[4096];
    int tid = threadIdx.x;
    int w = tid >> 6, lane = tid & 63;
    int wr = w >> 1, wc = w & 1;
    int lquad = lane >> 4, l15 = lane & 15;
    int mt = blockIdx.x >> 2, nt = blockIdx.x & 3;
    int m0 = mt * 128, n0 = nt * 128;

    int e0 = w * 512 + lane * 8;
    int r0 = e0 >> 5, ce = e0 & 31;
    const unsigned short* gA0 = A + (m0 + r0) * DIM + ce;
    const unsigned short* gA1 = gA0 + 64 * DIM;
    const unsigned short* gB0 = B + (n0 + r0) * DIM + ce;
    const unsigned short* gB1 = gB0 + 64 * DIM;
    unsigned short* lA0 = sA + w * 512;  unsigned short* lA1 = sA + (w + 4) * 512;
    unsigned short* lB0 = sB + w * 512;  unsigned short* lB1 = sB + (w + 4) * 512;

    int offA[4], offB[4];
    #pragma unroll
    for (int i = 0; i < 4; i++) {
        offA[i] = (wr * 64 + i * 16 + l15) * 32 + lquad * 8;
        offB[i] = (wc * 64 + i * 16 + l15) * 32 + lquad * 8;
    }

    f32x4 acc[4][4];
    #pragma unroll
    for (int mi = 0; mi < 4; mi++)
        #pragma unroll
        for (int ni = 0; ni < 4; ni++) acc[mi][ni] = 0;

    for (int kk = 0; kk < 16; kk++) {
        gl_lds16(gA0, lA0); gl_lds16(gA1, lA1);
        gl_lds16(gB0, lB0); gl_lds16(gB1, lB1);
        gA0 += 32; gA1 += 32; gB0 += 32; gB1 += 32;
        __syncthreads();
        short8 af[4], bf_[4];
        #pragma unroll
        for (int i = 0; i < 4; i++) {
            af[i]  = *(const short8*)&sA[offA[i]];
            bf_[i] = *(const short8*)&sB[offB[i]];
        }
        #pragma unroll
        for (int mi = 0; mi < 4; mi++)
            #pragma unroll
            for (int ni = 0; ni < 4; ni++)
                acc[mi][ni] = __builtin_amdgcn_mfma_f32_16x16x32_bf16(af[mi], bf_[ni], acc[mi][ni], 0, 0, 0);
        __syncthreads();
    }

    #pragma unroll
    for (int ni = 0; ni < 4; ni++) {
        int col = n0 + wc * 64 + ni * 16 + l15;
        float bv = b1[col];
        #pragma unroll
        for (int mi = 0; mi < 4; mi++) {
            int rowb = m0 + wr * 64 + mi * 16 + lquad * 4;
            #pragma unroll
            for (int rg = 0; rg < 4; rg++) {
                float v = acc[mi][ni][rg] + bv;
                v = v >= 0.f ? v : NEG * v;
                H[(rowb + rg) * DIM + col] = f2bf(v);
                H8[pack_addr(rowb + rg, col)] = f2fp8(v);
            }
        }
    }
}

// ---------------- fat GEMM: 4 waves x 32 rows, B LDS-broadcast 32-col tiles ----------------
// R9 barrier cadence (proven 163 us, zero spill) + fb ping-pong as the ONLY
// change: fA/fB register pairs let LOADH(kp+1) issue under MFMA4(kp).
// Regs ~156 <= 170 @ launch_bounds(256,3).
__launch_bounds__(256, 3)
__global__ void k_big(const unsigned char* __restrict__ Mel8,
                      const unsigned char* __restrict__ Emb8,
                      const unsigned char* __restrict__ H8,
                      const unsigned char* __restrict__ W28,
                      const float* __restrict__ enorm,
                      const float* __restrict__ b2,
                      float* __restrict__ p_s,
                      unsigned int* __restrict__ p_pmax,
                      unsigned int* __restrict__ p_pmin) {
    __shared__ __align__(16) unsigned char sB8[2][16384];
    __shared__ float sAux[1024];
    int tid = threadIdx.x;
    int w = tid >> 6, lane = tid & 63;
    int lquad = lane >> 4, l15 = lane & 15;
    int bid = blockIdx.x;
    int split = bid & 7;              // XCD-aligned: one split per XCD
    int is_logits = (bid >> 3) & 1;
    int mt = bid >> 4;                // 128 tiles of 128 rows
    int m0 = mt * 128, nbase = split * (NEMB / NSPLIT);

    const unsigned char* gAb = (is_logits ? H8 : Mel8);
    const unsigned char* gBb = (is_logits ? W28 : Emb8);

    // stage aux table (enorm-512 for dist, b2 for logits)
    #pragma unroll
    for (int j = 0; j < 4; j++) {
        int c = tid + j * 256;
        sAux[c] = is_logits ? b2[nbase + c] : (enorm[nbase + c] - 512.0f);
    }

    // A panel -> registers, once. Wave w owns rows [m0+32w, m0+32w+32).
    i32x8 fa8[2][4];
    #pragma unroll
    for (int mi = 0; mi < 2; mi++)
        #pragma unroll
        for (int kp = 0; kp < 4; kp++) {
            const unsigned char* p = gAb
                + ((size_t)(((m0 >> 4) + 2 * w + mi) * 8 + 2 * kp) << 10) + lane * 16;
            i32x4 lo = *(const i32x4*)p;
            i32x4 hi = *(const i32x4*)(p + 1024);
            fa8[mi][kp] = __builtin_shufflevector(lo, hi, 0, 1, 2, 3, 4, 5, 6, 7);
        }

    int uWd = w * 4096;  // wave's quarter of the 16 KB tile (bytes)
    const unsigned char* gB0p = gBb + (size_t)nbase * 512 + uWd + lane * 16;

    __syncthreads();     // aux visible; A/aux vmem drained (vmcnt clean for DMA)

    const f32x4 Z4 = {0.f, 0.f, 0.f, 0.f};
    f32x4 acc[2][2];
    i32x8 fA0, fA1, fB0, fB1;

    float s[8];
    unsigned int pbest[8];
    unsigned int pinit = is_logits ? 0u : 0xFFFFFFFFu;
    #pragma unroll
    for (int r = 0; r < 8; r++) { s[r] = 0.f; pbest[r] = pinit; }

    ISSUE_NT(0, 0);
    ISSUE_NT(1, 1);
    for (int nt = 0; nt < 32; nt++) {
        int cur = nt & 1;
        if (nt < 31) vm4_barrier(); else vm0_barrier();  // tile nt landed (all waves)
        COMPUTE(cur);
        lgkm_barrier();                 // all waves done reading buf[cur]
        if (nt + 2 < 32) ISSUE_NT(nt + 2, cur);  // refill freed buffer; flies under EPI
        EPILOGUE(nt);
    }

    // each row lives entirely in one wave: l15-group reduce, then direct store
    if (is_logits) {
        #pragma unroll
        for (int r = 0; r < 8; r++)
            #pragma unroll
            for (int d = 1; d < 16; d <<= 1) {
                s[r] += __shfl_xor(s[r], d);
                unsigned int o = (unsigned int)__shfl_xor((int)pbest[r], d);
                pbest[r] = pbest[r] > o ? pbest[r] : o;
            }
        if (l15 == 0) {
            #pragma unroll
            for (int mi = 0; mi < 2; mi++)
                #pragma unroll
                for (int rg = 0; rg < 4; rg++) {
                    int row = w * 32 + mi * 16 + lquad * 4 + rg;
                    int pidx = split * BSZ + m0 + row;
                    p_s[pidx] = s[mi * 4 + rg];
                    p_pmax[pidx] = pbest[mi * 4 + rg];
                }
        }
    } else {
        #pragma unroll
        for (int r = 0; r < 8; r++)
            #pragma unroll
            for (int d = 1; d < 16; d <<= 1) {
                unsigned int o = (unsigned int)__shfl_xor((int)pbest[r], d);
                pbest[r] = pbest[r] < o ? pbest[r] : o;
            }
        if (l15 == 0) {
            #pragma unroll
            for (int mi = 0; mi < 2; mi++)
                #pragma unroll
                for (int rg = 0; rg < 4; rg++) {
                    int row = w * 32 + mi * 16 + lquad * 4 + rg;
                    p_pmin[split * BSZ + m0 + row] = pbest[mi * 4 + rg];
                }
        }
    }
}

// ---------------- tail: merge + gather + global reduce, writes d_out ----------------
// 256 blocks x 64 rows: 4x resident waves, 16-iteration gather.
__global__ void k_tail(const float* __restrict__ p_s, const unsigned int* __restrict__ p_pmax,
                       const unsigned int* __restrict__ p_pmin,
                       const unsigned short* __restrict__ H,
                       const float* __restrict__ W2,
                       const float* __restrict__ b2,
                       float* __restrict__ acc2, int* __restrict__ cnt,
                       float* __restrict__ out) {
    __shared__ int s_idx[64];
    __shared__ float s_l1[64], s_match[64];
    __shared__ float s_d[4];
    int bid = blockIdx.x, tid = threadIdx.x;
    int w = tid >> 6, lane = tid & 63;
    int rbase = bid * 64;

    // merge: threads 0..63 each own one row
    if (tid < 64) {
        int r = rbase + tid;
        float S = 0.f; unsigned int PM = 0u, PN = 0xFFFFFFFFu;
        #pragma unroll
        for (int sp = 0; sp < NSPLIT; sp++) {
            S += p_s[sp * BSZ + r];
            unsigned int a = p_pmax[sp * BSZ + r];
            PM = PM > a ? PM : a;
            unsigned int b = p_pmin[sp * BSZ + r];
            PN = PN < b ? PN : b;
        }
        int eidx = (NEMB - 1) - (int)(PM & 0x1FFFu);
        int midx = (int)(PN & 0x1FFFu);
        s_idx[tid] = midx;
        s_l1[tid] = __logf(S) - b2[midx];
        s_match[tid] = (eidx == midx) ? 1.f : 0.f;
    }
    __syncthreads();

    // gather: wave w covers rows [w*16, w*16+16); independent iterations -> MLP
    float d0 = 0.f, d1 = 0.f;
    for (int j = 0; j < 16; j++) {
        int rr = w * 16 + j;
        int ridx = s_idx[rr];
        uint4 hv = *(const uint4*)(H + (size_t)(rbase + rr) * DIM + lane * 8);
        const float4* wp = (const float4*)(W2 + (size_t)ridx * DIM + lane * 8);
        float4 w0 = wp[0], w1 = wp[1];
        float p = bf2f((unsigned short)(hv.x & 0xffff)) * w0.x + bf2f((unsigned short)(hv.x >> 16)) * w0.y
                + bf2f((unsigned short)(hv.y & 0xffff)) * w0.z + bf2f((unsigned short)(hv.y >> 16)) * w0.w
                + bf2f((unsigned short)(hv.z & 0xffff)) * w1.x + bf2f((unsigned short)(hv.z >> 16)) * w1.y
                + bf2f((unsigned short)(hv.w & 0xffff)) * w1.z + bf2f((unsigned short)(hv.w >> 16)) * w1.w;
        if (j & 1) d1 += p; else d0 += p;
    }
    float ds = d0 + d1;
    #pragma unroll
    for (int d = 1; d < 64; d <<= 1) ds += __shfl_xor(ds, d);
    if (lane == 0) s_d[w] = ds;

    __syncthreads();
    for (int st = 32; st > 0; st >>= 1) {
        if (tid < st) { s_l1[tid] += s_l1[tid + st]; s_match[tid] += s_match[tid + st]; }
        __syncthreads();
    }
    if (tid == 0) {
        float loss_blk = s_l1[0] - (s_d[0] + s_d[1] + s_d[2] + s_d[3]);
        atomicAdd(&acc2[0], loss_blk * (1.0f / BSZ));
        atomicAdd(&acc2[1], s_match[0] * (1.0f / BSZ));
        __threadfence();
        if (atomicAdd(cnt, 1) == 255) {
            float L = atomicAdd(&acc2[0], 0.f);
            float M = atomicAdd(&acc2[1], 0.f);
            out[0] = L; out[1] = M;
        }
    }
}

extern "C" void kernel_launch(void* const* d_in, const int* in_sizes, int n_in,
                              void* d_out, int out_size, void* d_ws, size_t ws_size,
                              hipStream_t stream) {
    const float* eeg = (const float*)d_in[0];
    const float* mel = (const float*)d_in[1];
    const float* emb = (const float*)d_in[2];
    const float* W1  = (const float*)d_in[3];
    const float* b1  = (const float*)d_in[4];
    const float* W2  = (const float*)d_in[5];
    const float* b2  = (const float*)d_in[6];
    float* out = (float*)d_out;

    unsigned short* ws_eeg = (unsigned short*)d_ws;               // BSZ*DIM bf16
    unsigned short* ws_w1  = ws_eeg + (size_t)BSZ * DIM;          // DIM*DIM bf16
    unsigned short* ws_h   = ws_w1  + (size_t)DIM * DIM;          // BSZ*DIM bf16
    unsigned char*  ws_h8  = (unsigned char*)(ws_h + (size_t)BSZ * DIM);
    unsigned char*  ws_mel8 = ws_h8  + (size_t)BSZ * DIM;
    unsigned char*  ws_emb8 = ws_mel8 + (size_t)BSZ * DIM;
    unsigned char*  ws_w28  = ws_emb8 + (size_t)NEMB * DIM;
    float* ws_en  = (float*)(ws_w28 + (size_t)NEMB * DIM);
    float* p_s    = ws_en + NEMB;
    unsigned int* p_pmax = (unsigned int*)(p_s + (size_t)NSPLIT * BSZ);
    unsigned int* p_pmin = p_pmax + (size_t)NSPLIT * BSZ;
    float* acc2   = (float*)(p_pmin + (size_t)NSPLIT * BSZ);
    int*   cnt    = (int*)(acc2 + 2);

    k_prep<<<1024, 256, 0, stream>>>(eeg, mel, emb, W2, W1,
                                     ws_eeg, ws_w1, ws_mel8, ws_emb8, ws_w28,
                                     ws_en, acc2, cnt);
    k_hgemm<<<(BSZ / 128) * (DIM / 128), 256, 0, stream>>>(ws_eeg, ws_w1, b1, ws_h, ws_h8);
    k_big<<<(BSZ / 128) * NSPLIT * 2, 256, 0, stream>>>(ws_mel8, ws_emb8, ws_h8, ws_w28,
                                                        ws_en, b2, p_s, p_pmax, p_pmin);
    k_tail<<<BSZ / 64, 256, 0, stream>>>(p_s, p_pmax, p_pmin, ws_h, W2, b2, acc2, cnt, out);
}

// Round 13
// 325.352 us; speedup vs baseline: 1.0176x; 1.0013x over previous
//
#include <hip/hip_runtime.h>
#include <hip/hip_bf16.h>
#include <hip/hip_fp8.h>

#define BSZ 16384
#define DIM 512
#define NEMB 8192
#define NEG 0.01f
#define NSPLIT 8

typedef __attribute__((ext_vector_type(8))) short short8;
typedef __attribute__((ext_vector_type(4))) float f32x4;
typedef __attribute__((ext_vector_type(4))) int i32x4;
typedef __attribute__((ext_vector_type(8))) int i32x8;

typedef const __attribute__((address_space(1))) void GVT;
typedef __attribute__((address_space(3))) void LVT;

__device__ __forceinline__ void gl_lds16(const void* g, void* l) {
    __builtin_amdgcn_global_load_lds((GVT*)g, (LVT*)l, 16, 0, 0);
}

__device__ __forceinline__ float bf2f(unsigned short u) {
    union { unsigned int i; float f; } c; c.i = ((unsigned int)u) << 16; return c.f;
}
__device__ __forceinline__ unsigned short f2bf(float f) {
    union { __hip_bfloat16 h; unsigned short u; } c; c.h = __float2bfloat16(f); return c.u;
}
__device__ __forceinline__ unsigned char f2fp8(float f) {
    __hip_fp8_e4m3 t(f); return (unsigned char)t.__x;
}
// monotone-orderable uint key for a float
__device__ __forceinline__ unsigned int fkey(float f) {
    unsigned int u = __float_as_uint(f);
    return u ^ ((unsigned int)((int)u >> 31) | 0x80000000u);
}

// packed fragment address for element (r, k) of an [R x 512] fp8 matrix.
__device__ __forceinline__ size_t pack_addr(int r, int k) {
    int kg = k >> 6, ko = k & 63;
    int half = ko >> 5, lq = (ko & 31) >> 3, sub = ko & 7;
    int L = lq * 16 + (r & 15);
    return ((size_t)((r >> 4) * 8 + kg) << 10) + (size_t)(L << 4) + (half << 3) + sub;
}

// entry barrier: my 4 loads for the tile I'm about to read are done,
// next tile's 4 stay in flight (per-wave vmcnt + barrier = all waves' quarters in)
__device__ __forceinline__ void vm4_barrier() {
    asm volatile("s_waitcnt vmcnt(4) lgkmcnt(0)\ns_barrier" ::: "memory");
}
__device__ __forceinline__ void vm0_barrier() {
    asm volatile("s_waitcnt vmcnt(0) lgkmcnt(0)\ns_barrier" ::: "memory");
}
// exit barrier: all waves done reading the buffer (ds_reads drained)
__device__ __forceinline__ void lgkm_barrier() {
    asm volatile("s_waitcnt lgkmcnt(0)\ns_barrier" ::: "memory");
}

// stage one 32-col B tile (16 KB) into LDS buffer BUF: 4 DMA per wave
#define ISSUE_NT(NT, BUF) do { \
    const unsigned char* src_ = gB0p + (size_t)(NT) * 16384; \
    _Pragma("unroll") for (int i_ = 0; i_ < 4; i_++) \
        gl_lds16(src_ + i_ * 1024, &sB8[BUF][uWd + i_ * 1024]); \
} while (0)

// load the 2 column-fragments (ci=0,1) at K-pair KP from LDS tile CUR
#define LOADH(F0, F1, CUR, KP) do { \
    const unsigned char* lb_ = &sB8[CUR][(2 * (KP)) * 1024] + (lane << 4); \
    i32x4 a0_ = *(const i32x4*)lb_; \
    i32x4 a1_ = *(const i32x4*)(lb_ + 1024); \
    i32x4 b0_ = *(const i32x4*)(lb_ + 8192); \
    i32x4 b1_ = *(const i32x4*)(lb_ + 8192 + 1024); \
    F0 = __builtin_shufflevector(a0_, a1_, 0, 1, 2, 3, 4, 5, 6, 7); \
    F1 = __builtin_shufflevector(b0_, b1_, 0, 1, 2, 3, 4, 5, 6, 7); \
} while (0)

// 4 MFMAs: 2 mi row-groups x 2 ci. FIRST=1 -> zero C-in (no acc pre-zeroing).
#define MFMA4(F0, F1, KP, FIRST) do { \
    __builtin_amdgcn_s_setprio(1); \
    _Pragma("unroll") for (int mi = 0; mi < 2; mi++) { \
        f32x4 c0_ = (FIRST) ? Z4 : acc[mi][0]; \
        f32x4 c1_ = (FIRST) ? Z4 : acc[mi][1]; \
        acc[mi][0] = __builtin_amdgcn_mfma_scale_f32_16x16x128_f8f6f4( \
            fa8[mi][KP], F0, c0_, 0, 0, 0, 0x7F7F7F7Fu, 0, 0x7F7F7F7Fu); \
        acc[mi][1] = __builtin_amdgcn_mfma_scale_f32_16x16x128_f8f6f4( \
            fa8[mi][KP], F1, c1_, 0, 0, 0, 0x7F7F7F7Fu, 0, 0x7F7F7F7Fu); \
    } \
    __builtin_amdgcn_s_setprio(0); \
} while (0)

// K=512 for one 32-col tile
#define COMPUTE(CUR) do { \
    LOADH(fA0, fA1, CUR, 0); \
    LOADH(fB0, fB1, CUR, 1); \
    MFMA4(fA0, fA1, 0, 1); \
    LOADH(fA0, fA1, CUR, 2); \
    MFMA4(fB0, fB1, 1, 0); \
    LOADH(fB0, fB1, CUR, 3); \
    MFMA4(fA0, fA1, 2, 0); \
    MFMA4(fB0, fB1, 3, 0); \
} while (0)

// fold one 32-col tile into s/pbest: 2-col tree, one fkey pack per row.
#define EPILOGUE(NT) do { \
    int j0 = ((NT) << 5) + l15; \
    if (is_logits) { \
        float bb0 = sAux[j0], bb1 = sAux[j0 + 16]; \
        unsigned int ic0 = (unsigned int)(NEMB - 1 - (nbase + j0)); \
        _Pragma("unroll") for (int mi = 0; mi < 2; mi++) \
            _Pragma("unroll") for (int rg = 0; rg < 4; rg++) { \
                float v0 = acc[mi][0][rg] + bb0; \
                float v1 = acc[mi][1][rg] + bb1; \
                int r = mi * 4 + rg; \
                s[r] += __expf(v0) + __expf(v1); \
                float m = fmaxf(v0, v1); \
                unsigned int ii = v1 > v0 ? ic0 - 16 : ic0; \
                unsigned int pk = (fkey(m) & 0xFFFFE000u) | ii; \
                pbest[r] = pbest[r] > pk ? pbest[r] : pk; \
            } \
    } else { \
        float en0 = sAux[j0], en1 = sAux[j0 + 16]; \
        unsigned int cl0 = (unsigned int)(nbase + j0); \
        _Pragma("unroll") for (int mi = 0; mi < 2; mi++) \
            _Pragma("unroll") for (int rg = 0; rg < 4; rg++) { \
                float v0 = fmaf(-2.f, acc[mi][0][rg], en0); \
                float v1 = fmaf(-2.f, acc[mi][1][rg], en1); \
                float m = fminf(v0, v1); \
                unsigned int ii = v1 < v0 ? cl0 + 16 : cl0; \
                unsigned int pk = (fkey(m) & 0xFFFFE000u) | ii; \
                int r = mi * 4 + rg; \
                pbest[r] = pbest[r] < pk ? pbest[r] : pk; \
            } \
    } \
} while (0)

// ---------------- prep v3: 3-way partition, coalesced packed writes ----------------
// blocks [0,512): eeg+W1 -> bf16 linear (thread-stride float4).
// blocks [512,896): packed fp8 — one WAVE per 1 KB output unit: lane gathers
//   4 float4 from its row, converts 16 fp8, ONE uint4 store (wave = contiguous 1 KB).
// blocks [896,1024): enorm — one wave per row.
__global__ void k_prep(const float* __restrict__ eeg, const float* __restrict__ mel,
                       const float* __restrict__ emb, const float* __restrict__ W2,
                       const float* __restrict__ W1,
                       unsigned short* __restrict__ o_eeg, unsigned short* __restrict__ o_w1,
                       unsigned char* __restrict__ o_mel8, unsigned char* __restrict__ o_emb8,
                       unsigned char* __restrict__ o_w28,
                       float* __restrict__ enorm,
                       float* __restrict__ acc2, int* __restrict__ cnt) {
    int bid = blockIdx.x, tid = threadIdx.x;
    int w = tid >> 6, lane = tid & 63;
    if (bid == 0 && tid == 0) { acc2[0] = 0.f; acc2[1] = 0.f; *cnt = 0; }
    if (bid < 512) {
        const int n_big = BSZ * DIM / 4;
        const int n_w1  = DIM * DIM / 4;
        const int total = n_big + n_w1;
        for (int i = bid * 256 + tid; i < total; i += 512 * 256) {
            if (i < n_big) {
                float4 v = ((const float4*)eeg)[i];
                ushort4 o; o.x = f2bf(v.x); o.y = f2bf(v.y); o.z = f2bf(v.z); o.w = f2bf(v.w);
                ((ushort4*)o_eeg)[i] = o;
            } else {
                int j = i - n_big;
                float4 v = ((const float4*)W1)[j];
                ushort4 o; o.x = f2bf(v.x); o.y = f2bf(v.y); o.z = f2bf(v.z); o.w = f2bf(v.w);
                ((ushort4*)o_w1)[j] = o;
            }
        }
    } else if (bid < 896) {
        // units: mel 8192, emb 4096, w2 4096 (each unit = 16 rows x one kg = 1 KB out)
        int wid = (bid - 512) * 4 + w;
        for (int u = wid; u < 16384; u += 384 * 4) {
            const float* src; unsigned char* dst; int lu;
            if (u < 8192)       { src = mel; dst = o_mel8; lu = u; }
            else if (u < 12288) { src = emb; dst = o_emb8; lu = u - 8192; }
            else                { src = W2;  dst = o_w28;  lu = u - 12288; }
            int r  = ((lu >> 3) << 4) + (lane & 15);
            int kg = lu & 7;
            int f4 = r * 128 + kg * 16 + (lane >> 4) * 2;  // k0 = kg*64 + lq*8
            float4 f0 = ((const float4*)src)[f4];
            float4 f1 = ((const float4*)src)[f4 + 1];
            float4 f2 = ((const float4*)src)[f4 + 8];      // +32 floats
            float4 f3 = ((const float4*)src)[f4 + 9];
            union { unsigned char b[16]; uint4 v; } o;
            o.b[0]  = f2fp8(f0.x); o.b[1]  = f2fp8(f0.y); o.b[2]  = f2fp8(f0.z); o.b[3]  = f2fp8(f0.w);
            o.b[4]  = f2fp8(f1.x); o.b[5]  = f2fp8(f1.y); o.b[6]  = f2fp8(f1.z); o.b[7]  = f2fp8(f1.w);
            o.b[8]  = f2fp8(f2.x); o.b[9]  = f2fp8(f2.y); o.b[10] = f2fp8(f2.z); o.b[11] = f2fp8(f2.w);
            o.b[12] = f2fp8(f3.x); o.b[13] = f2fp8(f3.y); o.b[14] = f2fp8(f3.z); o.b[15] = f2fp8(f3.w);
            *(uint4*)(dst + (size_t)lu * 1024 + lane * 16) = o.v;
        }
    } else {
        int wid = (bid - 896) * 4 + w;
        for (int row = wid; row < NEMB; row += 128 * 4) {
            const float4* p = (const float4*)(emb + (size_t)row * DIM) + lane * 2;
            float4 a = p[0], b = p[1];
            float s = a.x*a.x + a.y*a.y + a.z*a.z + a.w*a.w
                    + b.x*b.x + b.y*b.y + b.z*b.z + b.w*b.w;
            #pragma unroll
            for (int d = 1; d < 64; d <<= 1) s += __shfl_xor(s, d);
            if (lane == 0) enorm[row] = s;
        }
    }
}

// ---------------- hgemm v3: 64x128 tiles, 1024 blocks (4/CU), K=64 stages ----------------
// Fragments staged as two K=32 sub-tiles (64-B row stride -> 2-way bank alias,
// free). 16 barriers/block (was 32), 4x the resident blocks.
__launch_bounds__(256, 4)
__global__ void k_hgemm(const unsigned short* __restrict__ A,
                        const unsigned short* __restrict__ B,
                        const float* __restrict__ b1,
                        unsigned short* __restrict__ H,
                        unsigned char* __restrict__ H8) {
    __shared__ __align__(16) unsigned short sA[2][2048], sB[2][4096];
    int tid = threadIdx.x;
    int w = tid >> 6, lane = tid & 63;
    int wr = w >> 1, wc = w & 1;
    int lquad = lane >> 4, l15 = lane & 15;
    int mt = blockIdx.x >> 2, nt = blockIdx.x & 3;
    int m0 = mt * 64, n0 = nt * 128;

    int e2 = w * 512 + lane * 8;      // 0..2040 shorts
    int rA = e2 >> 5, cA = e2 & 31;   // rA 0..63

    int offA[2], offB[4];
    #pragma unroll
    for (int i = 0; i < 2; i++) offA[i] = (wr * 32 + i * 16 + l15) * 32 + lquad * 8;
    #pragma unroll
    for (int i = 0; i < 4; i++) offB[i] = (wc * 64 + i * 16 + l15) * 32 + lquad * 8;

    f32x4 acc[2][4];
    #pragma unroll
    for (int mi = 0; mi < 2; mi++)
        #pragma unroll
        for (int ni = 0; ni < 4; ni++) acc[mi][ni] = 0;

    for (int kk = 0; kk < 8; kk++) {
        int kb = kk * 64;
        gl_lds16(A + (size_t)(m0 + rA) * DIM + kb + cA,        &sA[0][e2]);
        gl_lds16(A + (size_t)(m0 + rA) * DIM + kb + 32 + cA,   &sA[1][e2]);
        gl_lds16(B + (size_t)(n0 + rA) * DIM + kb + cA,        &sB[0][e2]);
        gl_lds16(B + (size_t)(n0 + rA + 64) * DIM + kb + cA,   &sB[0][e2 + 2048]);
        gl_lds16(B + (size_t)(n0 + rA) * DIM + kb + 32 + cA,   &sB[1][e2]);
        gl_lds16(B + (size_t)(n0 + rA + 64) * DIM + kb + 32 + cA, &sB[1][e2 + 2048]);
        __syncthreads();
        #pragma unroll
        for (int ks = 0; ks < 2; ks++) {
            short8 af[2], bf_[4];
            #pragma unroll
            for (int i = 0; i < 2; i++) af[i]  = *(const short8*)&sA[ks][offA[i]];
            #pragma unroll
            for (int i = 0; i < 4; i++) bf_[i] = *(const short8*)&sB[ks][offB[i]];
            #pragma unroll
            for (int mi = 0; mi < 2; mi++)
                #pragma unroll
                for (int ni = 0; ni < 4; ni++)
                    acc[mi][ni] = __builtin_amdgcn_mfma_f32_16x16x32_bf16(af[mi], bf_[ni], acc[mi][ni], 0, 0, 0);
        }
        __syncthreads();
    }

    #pragma unroll
    for (int ni = 0; ni < 4; ni++) {
        int col = n0 + wc * 64 + ni * 16 + l15;
        float bv = b1[col];
        #pragma unroll
        for (int mi = 0; mi < 2; mi++) {
            int rowb = m0 + wr * 32 + mi * 16 + lquad * 4;
            #pragma unroll
            for (int rg = 0; rg < 4; rg++) {
                float v = acc[mi][ni][rg] + bv;
                v = v >= 0.f ? v : NEG * v;
                H[(size_t)(rowb + rg) * DIM + col] = f2bf(v);
                H8[pack_addr(rowb + rg, col)] = f2fp8(v);
            }
        }
    }
}

// ---------------- fat GEMM: R12 kernel unchanged (163-169 us band) ----------------
__launch_bounds__(256, 3)
__global__ void k_big(const unsigned char* __restrict__ Mel8,
                      const unsigned char* __restrict__ Emb8,
                      const unsigned char* __restrict__ H8,
                      const unsigned char* __restrict__ W28,
                      const float* __restrict__ enorm,
                      const float* __restrict__ b2,
                      float* __restrict__ p_s,
                      unsigned int* __restrict__ p_pmax,
                      unsigned int* __restrict__ p_pmin) {
    __shared__ __align__(16) unsigned char sB8[2][16384];
    __shared__ float sAux[1024];
    int tid = threadIdx.x;
    int w = tid >> 6, lane = tid & 63;
    int lquad = lane >> 4, l15 = lane & 15;
    int bid = blockIdx.x;
    int split = bid & 7;              // XCD-aligned: one split per XCD
    int is_logits = (bid >> 3) & 1;
    int mt = bid >> 4;                // 128 tiles of 128 rows
    int m0 = mt * 128, nbase = split * (NEMB / NSPLIT);

    const unsigned char* gAb = (is_logits ? H8 : Mel8);
    const unsigned char* gBb = (is_logits ? W28 : Emb8);

    #pragma unroll
    for (int j = 0; j < 4; j++) {
        int c = tid + j * 256;
        sAux[c] = is_logits ? b2[nbase + c] : (enorm[nbase + c] - 512.0f);
    }

    i32x8 fa8[2][4];
    #pragma unroll
    for (int mi = 0; mi < 2; mi++)
        #pragma unroll
        for (int kp = 0; kp < 4; kp++) {
            const unsigned char* p = gAb
                + ((size_t)(((m0 >> 4) + 2 * w + mi) * 8 + 2 * kp) << 10) + lane * 16;
            i32x4 lo = *(const i32x4*)p;
            i32x4 hi = *(const i32x4*)(p + 1024);
            fa8[mi][kp] = __builtin_shufflevector(lo, hi, 0, 1, 2, 3, 4, 5, 6, 7);
        }

    int uWd = w * 4096;
    const unsigned char* gB0p = gBb + (size_t)nbase * 512 + uWd + lane * 16;

    __syncthreads();

    const f32x4 Z4 = {0.f, 0.f, 0.f, 0.f};
    f32x4 acc[2][2];
    i32x8 fA0, fA1, fB0, fB1;

    float s[8];
    unsigned int pbest[8];
    unsigned int pinit = is_logits ? 0u : 0xFFFFFFFFu;
    #pragma unroll
    for (int r = 0; r < 8; r++) { s[r] = 0.f; pbest[r] = pinit; }

    ISSUE_NT(0, 0);
    ISSUE_NT(1, 1);
    for (int nt = 0; nt < 32; nt++) {
        int cur = nt & 1;
        if (nt < 31) vm4_barrier(); else vm0_barrier();
        COMPUTE(cur);
        lgkm_barrier();
        if (nt + 2 < 32) ISSUE_NT(nt + 2, cur);
        EPILOGUE(nt);
    }

    if (is_logits) {
        #pragma unroll
        for (int r = 0; r < 8; r++)
            #pragma unroll
            for (int d = 1; d < 16; d <<= 1) {
                s[r] += __shfl_xor(s[r], d);
                unsigned int o = (unsigned int)__shfl_xor((int)pbest[r], d);
                pbest[r] = pbest[r] > o ? pbest[r] : o;
            }
        if (l15 == 0) {
            #pragma unroll
            for (int mi = 0; mi < 2; mi++)
                #pragma unroll
                for (int rg = 0; rg < 4; rg++) {
                    int row = w * 32 + mi * 16 + lquad * 4 + rg;
                    int pidx = split * BSZ + m0 + row;
                    p_s[pidx] = s[mi * 4 + rg];
                    p_pmax[pidx] = pbest[mi * 4 + rg];
                }
        }
    } else {
        #pragma unroll
        for (int r = 0; r < 8; r++)
            #pragma unroll
            for (int d = 1; d < 16; d <<= 1) {
                unsigned int o = (unsigned int)__shfl_xor((int)pbest[r], d);
                pbest[r] = pbest[r] < o ? pbest[r] : o;
            }
        if (l15 == 0) {
            #pragma unroll
            for (int mi = 0; mi < 2; mi++)
                #pragma unroll
                for (int rg = 0; rg < 4; rg++) {
                    int row = w * 32 + mi * 16 + lquad * 4 + rg;
                    p_pmin[split * BSZ + m0 + row] = pbest[mi * 4 + rg];
                }
        }
    }
}

// ---------------- tail: 256 blocks x 64 rows ----------------
__global__ void k_tail(const float* __restrict__ p_s, const unsigned int* __restrict__ p_pmax,
                       const unsigned int* __restrict__ p_pmin,
                       const unsigned short* __restrict__ H,
                       const float* __restrict__ W2,
                       const float* __restrict__ b2,
                       float* __restrict__ acc2, int* __restrict__ cnt,
                       float* __restrict__ out) {
    __shared__ int s_idx[64];
    __shared__ float s_l1[64], s_match[64];
    __shared__ float s_d[4];
    int bid = blockIdx.x, tid = threadIdx.x;
    int w = tid >> 6, lane = tid & 63;
    int rbase = bid * 64;

    if (tid < 64) {
        int r = rbase + tid;
        float S = 0.f; unsigned int PM = 0u, PN = 0xFFFFFFFFu;
        #pragma unroll
        for (int sp = 0; sp < NSPLIT; sp++) {
            S += p_s[sp * BSZ + r];
            unsigned int a = p_pmax[sp * BSZ + r];
            PM = PM > a ? PM : a;
            unsigned int b = p_pmin[sp * BSZ + r];
            PN = PN < b ? PN : b;
        }
        int eidx = (NEMB - 1) - (int)(PM & 0x1FFFu);
        int midx = (int)(PN & 0x1FFFu);
        s_idx[tid] = midx;
        s_l1[tid] = __logf(S) - b2[midx];
        s_match[tid] = (eidx == midx) ? 1.f : 0.f;
    }
    __syncthreads();

    float d0 = 0.f, d1 = 0.f;
    for (int j = 0; j < 16; j++) {
        int rr = w * 16 + j;
        int ridx = s_idx[rr];
        uint4 hv = *(const uint4*)(H + (size_t)(rbase + rr) * DIM + lane * 8);
        const float4* wp = (const float4*)(W2 + (size_t)ridx * DIM + lane * 8);
        float4 w0 = wp[0], w1 = wp[1];
        float p = bf2f((unsigned short)(hv.x & 0xffff)) * w0.x + bf2f((unsigned short)(hv.x >> 16)) * w0.y
                + bf2f((unsigned short)(hv.y & 0xffff)) * w0.z + bf2f((unsigned short)(hv.y >> 16)) * w0.w
                + bf2f((unsigned short)(hv.z & 0xffff)) * w1.x + bf2f((unsigned short)(hv.z >> 16)) * w1.y
                + bf2f((unsigned short)(hv.w & 0xffff)) * w1.z + bf2f((unsigned short)(hv.w >> 16)) * w1.w;
        if (j & 1) d1 += p; else d0 += p;
    }
    float ds = d0 + d1;
    #pragma unroll
    for (int d = 1; d < 64; d <<= 1) ds += __shfl_xor(ds, d);
    if (lane == 0) s_d[w] = ds;

    __syncthreads();
    for (int st = 32; st > 0; st >>= 1) {
        if (tid < st) { s_l1[tid] += s_l1[tid + st]; s_match[tid] += s_match[tid + st]; }
        __syncthreads();
    }
    if (tid == 0) {
        float loss_blk = s_l1[0] - (s_d[0] + s_d[1] + s_d[2] + s_d[3]);
        atomicAdd(&acc2[0], loss_blk * (1.0f / BSZ));
        atomicAdd(&acc2[1], s_match[0] * (1.0f / BSZ));
        __threadfence();
        if (atomicAdd(cnt, 1) == 255) {
            float L = atomicAdd(&acc2[0], 0.f);
            float M = atomicAdd(&acc2[1], 0.f);
            out[0] = L; out[1] = M;
        }
    }
}

extern "C" void kernel_launch(void* const* d_in, const int* in_sizes, int n_in,
                              void* d_out, int out_size, void* d_ws, size_t ws_size,
                              hipStream_t stream) {
    const float* eeg = (const float*)d_in[0];
    const float* mel = (const float*)d_in[1];
    const float* emb = (const float*)d_in[2];
    const float* W1  = (const float*)d_in[3];
    const float* b1  = (const float*)d_in[4];
    const float* W2  = (const float*)d_in[5];
    const float* b2  = (const float*)d_in[6];
    float* out = (float*)d_out;

    unsigned short* ws_eeg = (unsigned short*)d_ws;               // BSZ*DIM bf16
    unsigned short* ws_w1  = ws_eeg + (size_t)BSZ * DIM;          // DIM*DIM bf16
    unsigned short* ws_h   = ws_w1  + (size_t)DIM * DIM;          // BSZ*DIM bf16
    unsigned char*  ws_h8  = (unsigned char*)(ws_h + (size_t)BSZ * DIM);
    unsigned char*  ws_mel8 = ws_h8  + (size_t)BSZ * DIM;
    unsigned char*  ws_emb8 = ws_mel8 + (size_t)BSZ * DIM;
    unsigned char*  ws_w28  = ws_emb8 + (size_t)NEMB * DIM;
    float* ws_en  = (float*)(ws_w28 + (size_t)NEMB * DIM);
    float* p_s    = ws_en + NEMB;
    unsigned int* p_pmax = (unsigned int*)(p_s + (size_t)NSPLIT * BSZ);
    unsigned int* p_pmin = p_pmax + (size_t)NSPLIT * BSZ;
    float* acc2   = (float*)(p_pmin + (size_t)NSPLIT * BSZ);
    int*   cnt    = (int*)(acc2 + 2);

    k_prep<<<1024, 256, 0, stream>>>(eeg, mel, emb, W2, W1,
                                     ws_eeg, ws_w1, ws_mel8, ws_emb8, ws_w28,
                                     ws_en, acc2, cnt);
    k_hgemm<<<(BSZ / 64) * (DIM / 128), 256, 0, stream>>>(ws_eeg, ws_w1, b1, ws_h, ws_h8);
    k_big<<<(BSZ / 128) * NSPLIT * 2, 256, 0, stream>>>(ws_mel8, ws_emb8, ws_h8, ws_w28,
                                                        ws_en, b2, p_s, p_pmax, p_pmin);
    k_tail<<<BSZ / 64, 256, 0, stream>>>(p_s, p_pmax, p_pmin, ws_h, W2, b2, acc2, cnt, out);
}